// Round 4
// baseline (11314.983 us; speedup 1.0000x reference)
//
#include <hip/hip_runtime.h>
#include <stdint.h>

// SkipGRU: T=384, B=48, C=H=256, L=2.
// GEMM(gi = x@W_ih^T + b_ih) -> pairwise-WG recurrence -> GEMM -> recurrence.
//
// Recurrence r4: J=2 batch interleave. 24 pairs x 2 WGs = 48 WGs; the two WGs
// of a pair (blk, blk+24 -> same XCD under round-robin %8) each own half of
// W_hh and process the SAME two batches {2*pair, 2*pair+1}. Rationale: r3
// showed the per-step cost (~5800 cyc) is dominated by per-STEP overheads --
// cross-WG exchange flight, B1 vmcnt drain, barrier jitter, and W operand
// re-fetch (VGPR_Count=128 < 192 regs needed => W is partially re-streamed
// every step). All of these are amortized over 2 independent recurrences:
// exchanges fly concurrently, one barrier set serves both, and the matvec is
// interleaved at the fragment level so each W fragment is fetched ONCE and
// used for both batches' FMAs.
//
// Exchange protocol (r2, verified): self-synchronizing tagged u64 words
// ((tag<<32)|float_bits), relaxed agent-scope, double-buffered by step parity;
// dns = sigm(pd_p + pd_q + lb) is commutative -> bit-identical skip
// trajectories in both WGs -> lockstep, no deadlock.

#define T_STEPS 384
#define BATCH   48
#define HID     256

__device__ __forceinline__ float sigm_(float x) { return 1.f / (1.f + __expf(-x)); }
__device__ __forceinline__ float tanh_(float x) {
    float ax = fabsf(x);
    float e  = __expf(-2.f * ax);
    float r  = (1.f - e) / (1.f + e);
    return copysignf(r, x);
}

// ---------------------------------------------------------------------------
// GEMM: O[m][n] = sum_k X[m][k] * W[n][k] + B[n];  M=18432, N=768, K=256.
// grid (12, 144), block 256. Tile 128(M) x 64(N), K-chunks of 32 staged in LDS.
// (unchanged; ~140 us each, not the current bottleneck)
// ---------------------------------------------------------------------------
__global__ __launch_bounds__(256, 2) void gemm_nt(const float* __restrict__ X,
                                                  const float* __restrict__ W,
                                                  const float* __restrict__ B,
                                                  float* __restrict__ O)
{
    __shared__ float As[32 * 140];
    __shared__ float Bs[32 * 68];

    const int tid = threadIdx.x;
    const int tx  = tid & 15;
    const int ty  = tid >> 4;
    const int n0  = blockIdx.x * 64;
    const int m0  = blockIdx.y * 128;

    float acc[8][4];
#pragma unroll
    for (int i = 0; i < 8; ++i)
#pragma unroll
        for (int j = 0; j < 4; ++j) acc[i][j] = 0.f;

    const float4 bias4 = *reinterpret_cast<const float4*>(B + n0 + tx * 4);

    for (int kc = 0; kc < 8; ++kc) {
        const int k0 = kc * 32;
        float4 a[4], bb[2];
#pragma unroll
        for (int j = 0; j < 4; ++j) {
            int f = tid + 256 * j, r = f >> 3, cq = f & 7;
            a[j] = *reinterpret_cast<const float4*>(X + (size_t)(m0 + r) * 256 + k0 + cq * 4);
        }
#pragma unroll
        for (int j = 0; j < 2; ++j) {
            int f = tid + 256 * j, r = f >> 3, cq = f & 7;
            bb[j] = *reinterpret_cast<const float4*>(W + (size_t)(n0 + r) * 256 + k0 + cq * 4);
        }
        __syncthreads();
#pragma unroll
        for (int j = 0; j < 4; ++j) {
            int f = tid + 256 * j, r = f >> 3, cq = f & 7;
            As[(cq * 4 + 0) * 140 + r] = a[j].x;
            As[(cq * 4 + 1) * 140 + r] = a[j].y;
            As[(cq * 4 + 2) * 140 + r] = a[j].z;
            As[(cq * 4 + 3) * 140 + r] = a[j].w;
        }
#pragma unroll
        for (int j = 0; j < 2; ++j) {
            int f = tid + 256 * j, r = f >> 3, cq = f & 7;
            Bs[(cq * 4 + 0) * 68 + r] = bb[j].x;
            Bs[(cq * 4 + 1) * 68 + r] = bb[j].y;
            Bs[(cq * 4 + 2) * 68 + r] = bb[j].z;
            Bs[(cq * 4 + 3) * 68 + r] = bb[j].w;
        }
        __syncthreads();
#pragma unroll 8
        for (int kk = 0; kk < 32; ++kk) {
            float4 av0 = *reinterpret_cast<const float4*>(As + kk * 140 + ty * 8);
            float4 av1 = *reinterpret_cast<const float4*>(As + kk * 140 + ty * 8 + 4);
            float4 bv  = *reinterpret_cast<const float4*>(Bs + kk * 68 + tx * 4);
            float am[8] = {av0.x, av0.y, av0.z, av0.w, av1.x, av1.y, av1.z, av1.w};
            float bn[4] = {bv.x, bv.y, bv.z, bv.w};
#pragma unroll
            for (int i = 0; i < 8; ++i)
#pragma unroll
                for (int j = 0; j < 4; ++j) acc[i][j] = fmaf(am[i], bn[j], acc[i][j]);
        }
    }
#pragma unroll
    for (int i = 0; i < 8; ++i) {
        int row = m0 + ty * 8 + i;
        float4 o;
        o.x = acc[i][0] + bias4.x;
        o.y = acc[i][1] + bias4.y;
        o.z = acc[i][2] + bias4.z;
        o.w = acc[i][3] + bias4.w;
        *reinterpret_cast<float4*>(O + (size_t)row * 768 + n0 + tx * 4) = o;
    }
}

// ---------------------------------------------------------------------------
// Recurrence. grid = 48, block 512. pair = blk%24, p = blk/24, batches
// b0=2*pair, b1=2*pair+1. Wave w (0..7), g=lane&15 -> column c = p*128+w*16+g.
// Sub s=lane>>4: own k-slice [p*128+s*32,+32), partner [q*128+s*32,+32);
// W: 48 float4/lane. hbuf per batch: double-buffered x 4 shifted copies
// (stride 264) -> conflict-free broadcast b128 reads.
// Per step: P1 {gates+publish+butterfly per batch} B1 {ownpd+PD publish, poll
// issue, gi prefetch, own-half matvec (W-interleaved over both batches), poll
// complete + LDS write} B2 {PD poll issue, partner-half matvec (interleaved),
// fold, dns, state}.
// ---------------------------------------------------------------------------
__global__ __launch_bounds__(512, 2) void rec_layer(
    const float* __restrict__ GI, float* __restrict__ Yout,
    const float* __restrict__ whh, const float* __restrict__ bhh,
    const float* __restrict__ lwl, const float* __restrict__ lbl,
    const float* __restrict__ hid,
    unsigned long long* XH, unsigned long long* PD,
    float* __restrict__ hsout, float* __restrict__ tuout)
{
    __shared__ float hbuf[2][2112];   // per batch: 2 parities x (4 copies x 264)
    __shared__ float pdw[2][2][8];    // per batch, per slot, per wave

    const int tid  = threadIdx.x;
    const int lane = tid & 63;
    const int w    = tid >> 6;
    const int g    = lane & 15;
    const int s    = lane >> 4;
    const int pair = blockIdx.x % 24;
    const int p    = blockIdx.x / 24;   // blk and blk+24: same XCD under %8 round-robin
    const int q    = 1 - p;
    const int b0   = pair * 2;
    const int b1   = b0 + 1;
    const int c    = p * 128 + w * 16 + g;

    // W_hh fragments (own-k and partner-k sub-slices)
    float4 WrO[8], WzO[8], WnO[8], WrP[8], WzP[8], WnP[8];
    {
        const size_t rR = (size_t)c * 256;
        const size_t rZ = (size_t)(256 + c) * 256;
        const size_t rN = (size_t)(512 + c) * 256;
        const int ko = p * 128 + s * 32;
        const int kq = q * 128 + s * 32;
        const float4* a  = reinterpret_cast<const float4*>(whh + rR + ko);
        const float4* bv = reinterpret_cast<const float4*>(whh + rZ + ko);
        const float4* cv = reinterpret_cast<const float4*>(whh + rN + ko);
        const float4* d4 = reinterpret_cast<const float4*>(whh + rR + kq);
        const float4* e4 = reinterpret_cast<const float4*>(whh + rZ + kq);
        const float4* f4 = reinterpret_cast<const float4*>(whh + rN + kq);
#pragma unroll
        for (int i = 0; i < 8; ++i) {
            WrO[i] = a[i];  WzO[i] = bv[i]; WnO[i] = cv[i];
            WrP[i] = d4[i]; WzP[i] = e4[i]; WnP[i] = f4[i];
        }
    }

    const float bhr = bhh[c], bhz = bhh[256 + c], bhn = bhh[512 + c];
    const float lwc = lwl[c];
    const float lbv = lbl[0];

    if (tid < 256) {
        float v = hid[tid];
        hbuf[0][tid] = v; hbuf[0][264 + tid] = v; hbuf[0][528 + tid] = v; hbuf[0][792 + tid] = v;
        hbuf[1][tid] = v; hbuf[1][264 + tid] = v; hbuf[1][528 + tid] = v; hbuf[1][792 + tid] = v;
    }
    __syncthreads();

    // prologue: gi(0) per batch; stash A(0) (identical for both batches: same h0, same W)
    float gir0, giz0, gin0, gir1, giz1, gin1;
    {
        const size_t ga = (size_t)b0 * 768 + c;
        const size_t gb = (size_t)b1 * 768 + c;
        gir0 = GI[ga]; giz0 = GI[ga + 256]; gin0 = GI[ga + 512];
        gir1 = GI[gb]; giz1 = GI[gb + 256]; gin1 = GI[gb + 512];
    }
    float sAr0, sAz0, sAn0, sAr1, sAz1, sAn1;
    {
        float ar = 0.f, az = 0.f, an = 0.f;
        const float4* ho = reinterpret_cast<const float4*>(&hbuf[0][0] + s * 264 + p * 128 + s * 32);
        const float4* hq = reinterpret_cast<const float4*>(&hbuf[0][0] + s * 264 + q * 128 + s * 32);
#pragma unroll
        for (int i = 0; i < 8; ++i) {
            float4 hv = ho[i];
            ar = fmaf(WrO[i].x, hv.x, ar); ar = fmaf(WrO[i].y, hv.y, ar);
            ar = fmaf(WrO[i].z, hv.z, ar); ar = fmaf(WrO[i].w, hv.w, ar);
            az = fmaf(WzO[i].x, hv.x, az); az = fmaf(WzO[i].y, hv.y, az);
            az = fmaf(WzO[i].z, hv.z, az); az = fmaf(WzO[i].w, hv.w, az);
            an = fmaf(WnO[i].x, hv.x, an); an = fmaf(WnO[i].y, hv.y, an);
            an = fmaf(WnO[i].z, hv.z, an); an = fmaf(WnO[i].w, hv.w, an);
        }
#pragma unroll
        for (int i = 0; i < 8; ++i) {
            float4 hv = hq[i];
            ar = fmaf(WrP[i].x, hv.x, ar); ar = fmaf(WrP[i].y, hv.y, ar);
            ar = fmaf(WrP[i].z, hv.z, ar); ar = fmaf(WrP[i].w, hv.w, ar);
            az = fmaf(WzP[i].x, hv.x, az); az = fmaf(WzP[i].y, hv.y, az);
            az = fmaf(WzP[i].z, hv.z, az); az = fmaf(WzP[i].w, hv.w, az);
            an = fmaf(WnP[i].x, hv.x, an); an = fmaf(WnP[i].y, hv.y, an);
            an = fmaf(WnP[i].w, hv.w, an); an = fmaf(WnP[i].z, hv.z, an);
        }
        ar += __shfl_xor(ar, 16); ar += __shfl_xor(ar, 32);
        az += __shfl_xor(az, 16); az += __shfl_xor(az, 32);
        an += __shfl_xor(an, 16); an += __shfl_xor(an, 32);
        sAr0 = ar; sAz0 = az; sAn0 = an;
        sAr1 = ar; sAz1 = az; sAn1 = an;
    }

    float u0 = 1.f, d0 = 0.f, u1 = 1.f, d1 = 0.f;
    bool  sk0 = false, sk1 = false;
    int   ns0 = 0, ns1 = 0;
    int   hp0 = 0, hp1 = 0;

    unsigned long long* XHb0 = XH + b0 * 512;
    unsigned long long* XHb1 = XH + b1 * 512;
    unsigned long long* PDb0 = PD + b0 * 4;
    unsigned long long* PDb1 = PD + b1 * 4;

    for (int t = 0; t < T_STEPS; ++t) {
        const int tp = (t < T_STEPS - 1) ? t + 1 : t;
        const bool k0 = sk0, k1 = sk1;                 // captured at step start
        const float bu0 = rintf(u0), obu0 = 1.f - bu0;
        const float bu1 = rintf(u1), obu1 = 1.f - bu1;
        const int sl0 = ns0 & 1, sl1 = ns1 & 1;
        const unsigned int tag0 = (unsigned int)ns0 + 1u;
        const unsigned int tag1 = (unsigned int)ns1 + 1u;
        const size_t yrow0 = ((size_t)t * 48 + b0) * 256;
        const size_t yrow1 = ((size_t)t * 48 + b1) * 256;
        float* hbn0 = &hbuf[0][(hp0 ^ 1) * 1056];
        float* hbn1 = &hbuf[1][(hp1 ^ 1) * 1056];

        // ------------------------- phase 1 -------------------------
        if (!k0) {
            float hcv = hbuf[0][hp0 * 1056 + s * 264 + c];
            float rr  = sigm_(gir0 + sAr0 + bhr);
            float zz  = sigm_(giz0 + sAz0 + bhz);
            float tn  = tanh_(gin0 + rr * (sAn0 + bhn));
            float nh  = ((1.f - zz) * tn + zz * hcv) * bu0;
            float pdv = nh * lwc;
            if (s == 0) {
                unsigned long long pk = ((unsigned long long)tag0 << 32) |
                                        (unsigned long long)__float_as_uint(nh);
                __hip_atomic_store(XHb0 + sl0 * 256 + c, pk, __ATOMIC_RELAXED, __HIP_MEMORY_SCOPE_AGENT);
                hbn0[c] = nh; hbn0[264 + c] = nh; hbn0[528 + c] = nh; hbn0[792 + c] = nh;
                Yout[yrow0 + c] = nh;
                if (t == T_STEPS - 1) hsout[b0 * 256 + c] = nh;
            }
            pdv += __shfl_xor(pdv, 1);  pdv += __shfl_xor(pdv, 2);  pdv += __shfl_xor(pdv, 4);
            pdv += __shfl_xor(pdv, 8);  pdv += __shfl_xor(pdv, 16); pdv += __shfl_xor(pdv, 32);
            pdv *= 0.25f;
            if (lane == 0) pdw[0][sl0][w] = pdv;
            if (p == 0 && tid == 0) tuout[b0 * 768 + t] = bu0;
        } else {
            float* hb = &hbuf[0][hp0 * 1056];
            if (s == 0) {
                float hcv = hb[c];
                float nh  = hcv * obu0;
                if (bu0 != 0.f) { hb[c] = nh; hb[264 + c] = nh; hb[528 + c] = nh; hb[792 + c] = nh; }
                Yout[yrow0 + c] = nh;
                if (t == T_STEPS - 1) hsout[b0 * 256 + c] = nh;
            }
            if (bu0 != 0.f) { sAr0 = 0.f; sAz0 = 0.f; sAn0 = 0.f; }
            if (p == 0 && tid == 0) tuout[b0 * 768 + t] = bu0;
            u0  = fminf(fmaxf(u0 + d0, 0.f), 1.f) * obu0;
            sk0 = (u0 < 0.5f);
        }
        if (!k1) {
            float hcv = hbuf[1][hp1 * 1056 + s * 264 + c];
            float rr  = sigm_(gir1 + sAr1 + bhr);
            float zz  = sigm_(giz1 + sAz1 + bhz);
            float tn  = tanh_(gin1 + rr * (sAn1 + bhn));
            float nh  = ((1.f - zz) * tn + zz * hcv) * bu1;
            float pdv = nh * lwc;
            if (s == 0) {
                unsigned long long pk = ((unsigned long long)tag1 << 32) |
                                        (unsigned long long)__float_as_uint(nh);
                __hip_atomic_store(XHb1 + sl1 * 256 + c, pk, __ATOMIC_RELAXED, __HIP_MEMORY_SCOPE_AGENT);
                hbn1[c] = nh; hbn1[264 + c] = nh; hbn1[528 + c] = nh; hbn1[792 + c] = nh;
                Yout[yrow1 + c] = nh;
                if (t == T_STEPS - 1) hsout[b1 * 256 + c] = nh;
            }
            pdv += __shfl_xor(pdv, 1);  pdv += __shfl_xor(pdv, 2);  pdv += __shfl_xor(pdv, 4);
            pdv += __shfl_xor(pdv, 8);  pdv += __shfl_xor(pdv, 16); pdv += __shfl_xor(pdv, 32);
            pdv *= 0.25f;
            if (lane == 0) pdw[1][sl1][w] = pdv;
            if (p == 0 && tid == 0) tuout[b1 * 768 + t] = bu1;
        } else {
            float* hb = &hbuf[1][hp1 * 1056];
            if (s == 0) {
                float hcv = hb[c];
                float nh  = hcv * obu1;
                if (bu1 != 0.f) { hb[c] = nh; hb[264 + c] = nh; hb[528 + c] = nh; hb[792 + c] = nh; }
                Yout[yrow1 + c] = nh;
                if (t == T_STEPS - 1) hsout[b1 * 256 + c] = nh;
            }
            if (bu1 != 0.f) { sAr1 = 0.f; sAz1 = 0.f; sAn1 = 0.f; }
            if (p == 0 && tid == 0) tuout[b1 * 768 + t] = bu1;
            u1  = fminf(fmaxf(u1 + d1, 0.f), 1.f) * obu1;
            sk1 = (u1 < 0.5f);
        }
        __syncthreads();  // B1: publishes drained (vmcnt), own halves + pdw visible

        // ------------------------- phase 2 -------------------------
        float ownpd0 = 0.f, ownpd1 = 0.f;
        if (!k0) {
            ownpd0 = ((pdw[0][sl0][0] + pdw[0][sl0][1]) + (pdw[0][sl0][2] + pdw[0][sl0][3]))
                   + ((pdw[0][sl0][4] + pdw[0][sl0][5]) + (pdw[0][sl0][6] + pdw[0][sl0][7]));
            if (tid == 0) {
                unsigned long long pk = ((unsigned long long)tag0 << 32) |
                                        (unsigned long long)__float_as_uint(ownpd0);
                __hip_atomic_store(PDb0 + sl0 * 2 + p, pk, __ATOMIC_RELAXED, __HIP_MEMORY_SCOPE_AGENT);
            }
        }
        if (!k1) {
            ownpd1 = ((pdw[1][sl1][0] + pdw[1][sl1][1]) + (pdw[1][sl1][2] + pdw[1][sl1][3]))
                   + ((pdw[1][sl1][4] + pdw[1][sl1][5]) + (pdw[1][sl1][6] + pdw[1][sl1][7]));
            if (tid == 0) {
                unsigned long long pk = ((unsigned long long)tag1 << 32) |
                                        (unsigned long long)__float_as_uint(ownpd1);
                __hip_atomic_store(PDb1 + sl1 * 2 + p, pk, __ATOMIC_RELAXED, __HIP_MEMORY_SCOPE_AGENT);
            }
        }
        // issue partner polls early; their flight hides under gi prefetch + matvec
        unsigned long long pk0 = 0, pk1 = 0;
        if (tid < 128) {
            if (!k0) pk0 = __hip_atomic_load(XHb0 + sl0 * 256 + q * 128 + tid, __ATOMIC_RELAXED, __HIP_MEMORY_SCOPE_AGENT);
            if (!k1) pk1 = __hip_atomic_load(XHb1 + sl1 * 256 + q * 128 + tid, __ATOMIC_RELAXED, __HIP_MEMORY_SCOPE_AGENT);
        }
        const size_t gp0 = ((size_t)tp * 48 + b0) * 768 + c;
        const size_t gp1 = ((size_t)tp * 48 + b1) * 768 + c;
        float nr0 = GI[gp0], nz0 = GI[gp0 + 256], ng0 = GI[gp0 + 512];
        float nr1 = GI[gp1], nz1 = GI[gp1 + 256], ng1 = GI[gp1 + 512];

        // own-half matvec of A(t+1); W fragments fetched once, used for both batches
        float ar0 = 0.f, az0 = 0.f, an0 = 0.f, ar1 = 0.f, az1 = 0.f, an1 = 0.f;
        if (!k0 && !k1) {
            const float4* h0 = reinterpret_cast<const float4*>(hbn0 + s * 264 + p * 128 + s * 32);
            const float4* h1 = reinterpret_cast<const float4*>(hbn1 + s * 264 + p * 128 + s * 32);
#pragma unroll
            for (int i = 0; i < 8; ++i) {
                float4 v0 = h0[i], v1 = h1[i];
                float4 wr = WrO[i], wz = WzO[i], wn = WnO[i];
                ar0 = fmaf(wr.x, v0.x, ar0); ar0 = fmaf(wr.y, v0.y, ar0);
                ar0 = fmaf(wr.z, v0.z, ar0); ar0 = fmaf(wr.w, v0.w, ar0);
                ar1 = fmaf(wr.x, v1.x, ar1); ar1 = fmaf(wr.y, v1.y, ar1);
                ar1 = fmaf(wr.z, v1.z, ar1); ar1 = fmaf(wr.w, v1.w, ar1);
                az0 = fmaf(wz.x, v0.x, az0); az0 = fmaf(wz.y, v0.y, az0);
                az0 = fmaf(wz.z, v0.z, az0); az0 = fmaf(wz.w, v0.w, az0);
                az1 = fmaf(wz.x, v1.x, az1); az1 = fmaf(wz.y, v1.y, az1);
                az1 = fmaf(wz.z, v1.z, az1); az1 = fmaf(wz.w, v1.w, az1);
                an0 = fmaf(wn.x, v0.x, an0); an0 = fmaf(wn.y, v0.y, an0);
                an0 = fmaf(wn.z, v0.z, an0); an0 = fmaf(wn.w, v0.w, an0);
                an1 = fmaf(wn.x, v1.x, an1); an1 = fmaf(wn.y, v1.y, an1);
                an1 = fmaf(wn.z, v1.z, an1); an1 = fmaf(wn.w, v1.w, an1);
            }
        } else if (!k0) {
            const float4* h0 = reinterpret_cast<const float4*>(hbn0 + s * 264 + p * 128 + s * 32);
#pragma unroll
            for (int i = 0; i < 8; ++i) {
                float4 v0 = h0[i];
                ar0 = fmaf(WrO[i].x, v0.x, ar0); ar0 = fmaf(WrO[i].y, v0.y, ar0);
                ar0 = fmaf(WrO[i].z, v0.z, ar0); ar0 = fmaf(WrO[i].w, v0.w, ar0);
                az0 = fmaf(WzO[i].x, v0.x, az0); az0 = fmaf(WzO[i].y, v0.y, az0);
                az0 = fmaf(WzO[i].z, v0.z, az0); az0 = fmaf(WzO[i].w, v0.w, az0);
                an0 = fmaf(WnO[i].x, v0.x, an0); an0 = fmaf(WnO[i].y, v0.y, an0);
                an0 = fmaf(WnO[i].z, v0.z, an0); an0 = fmaf(WnO[i].w, v0.w, an0);
            }
        } else if (!k1) {
            const float4* h1 = reinterpret_cast<const float4*>(hbn1 + s * 264 + p * 128 + s * 32);
#pragma unroll
            for (int i = 0; i < 8; ++i) {
                float4 v1 = h1[i];
                ar1 = fmaf(WrO[i].x, v1.x, ar1); ar1 = fmaf(WrO[i].y, v1.y, ar1);
                ar1 = fmaf(WrO[i].z, v1.z, ar1); ar1 = fmaf(WrO[i].w, v1.w, ar1);
                az1 = fmaf(WzO[i].x, v1.x, az1); az1 = fmaf(WzO[i].y, v1.y, az1);
                az1 = fmaf(WzO[i].z, v1.z, az1); az1 = fmaf(WzO[i].w, v1.w, az1);
                an1 = fmaf(WnO[i].x, v1.x, an1); an1 = fmaf(WnO[i].y, v1.y, an1);
                an1 = fmaf(WnO[i].z, v1.z, an1); an1 = fmaf(WnO[i].w, v1.w, an1);
            }
        }
        // complete polls, install partner halves
        if (tid < 128) {
            const int qc = q * 128 + tid;
            if (!k0) {
                while ((unsigned int)(pk0 >> 32) < tag0)
                    pk0 = __hip_atomic_load(XHb0 + sl0 * 256 + qc, __ATOMIC_RELAXED, __HIP_MEMORY_SCOPE_AGENT);
                float v = __uint_as_float((unsigned int)pk0);
                hbn0[qc] = v; hbn0[264 + qc] = v; hbn0[528 + qc] = v; hbn0[792 + qc] = v;
            }
            if (!k1) {
                while ((unsigned int)(pk1 >> 32) < tag1)
                    pk1 = __hip_atomic_load(XHb1 + sl1 * 256 + qc, __ATOMIC_RELAXED, __HIP_MEMORY_SCOPE_AGENT);
                float v = __uint_as_float((unsigned int)pk1);
                hbn1[qc] = v; hbn1[264 + qc] = v; hbn1[528 + qc] = v; hbn1[792 + qc] = v;
            }
        }
        __syncthreads();  // B2: partner halves in place

        // ------------------------- phase 3 -------------------------
        unsigned long long pq0 = 0, pq1 = 0;
        if (!k0) pq0 = __hip_atomic_load(PDb0 + sl0 * 2 + q, __ATOMIC_RELAXED, __HIP_MEMORY_SCOPE_AGENT);
        if (!k1) pq1 = __hip_atomic_load(PDb1 + sl1 * 2 + q, __ATOMIC_RELAXED, __HIP_MEMORY_SCOPE_AGENT);

        if (!k0 && !k1) {
            const float4* h0 = reinterpret_cast<const float4*>(hbn0 + s * 264 + q * 128 + s * 32);
            const float4* h1 = reinterpret_cast<const float4*>(hbn1 + s * 264 + q * 128 + s * 32);
#pragma unroll
            for (int i = 0; i < 8; ++i) {
                float4 v0 = h0[i], v1 = h1[i];
                float4 wr = WrP[i], wz = WzP[i], wn = WnP[i];
                ar0 = fmaf(wr.x, v0.x, ar0); ar0 = fmaf(wr.y, v0.y, ar0);
                ar0 = fmaf(wr.z, v0.z, ar0); ar0 = fmaf(wr.w, v0.w, ar0);
                ar1 = fmaf(wr.x, v1.x, ar1); ar1 = fmaf(wr.y, v1.y, ar1);
                ar1 = fmaf(wr.z, v1.z, ar1); ar1 = fmaf(wr.w, v1.w, ar1);
                az0 = fmaf(wz.x, v0.x, az0); az0 = fmaf(wz.y, v0.y, az0);
                az0 = fmaf(wz.z, v0.z, az0); az0 = fmaf(wz.w, v0.w, az0);
                az1 = fmaf(wz.x, v1.x, az1); az1 = fmaf(wz.y, v1.y, az1);
                az1 = fmaf(wz.z, v1.z, az1); az1 = fmaf(wz.w, v1.w, az1);
                an0 = fmaf(wn.x, v0.x, an0); an0 = fmaf(wn.y, v0.y, an0);
                an0 = fmaf(wn.z, v0.z, an0); an0 = fmaf(wn.w, v0.w, an0);
                an1 = fmaf(wn.x, v1.x, an1); an1 = fmaf(wn.y, v1.y, an1);
                an1 = fmaf(wn.z, v1.z, an1); an1 = fmaf(wn.w, v1.w, an1);
            }
        } else if (!k0) {
            const float4* h0 = reinterpret_cast<const float4*>(hbn0 + s * 264 + q * 128 + s * 32);
#pragma unroll
            for (int i = 0; i < 8; ++i) {
                float4 v0 = h0[i];
                ar0 = fmaf(WrP[i].x, v0.x, ar0); ar0 = fmaf(WrP[i].y, v0.y, ar0);
                ar0 = fmaf(WrP[i].z, v0.z, ar0); ar0 = fmaf(WrP[i].w, v0.w, ar0);
                az0 = fmaf(WzP[i].x, v0.x, az0); az0 = fmaf(WzP[i].y, v0.y, az0);
                az0 = fmaf(WzP[i].z, v0.z, az0); az0 = fmaf(WzP[i].w, v0.w, az0);
                an0 = fmaf(WnP[i].x, v0.x, an0); an0 = fmaf(WnP[i].y, v0.y, an0);
                an0 = fmaf(WnP[i].z, v0.z, an0); an0 = fmaf(WnP[i].w, v0.w, an0);
            }
        } else if (!k1) {
            const float4* h1 = reinterpret_cast<const float4*>(hbn1 + s * 264 + q * 128 + s * 32);
#pragma unroll
            for (int i = 0; i < 8; ++i) {
                float4 v1 = h1[i];
                ar1 = fmaf(WrP[i].x, v1.x, ar1); ar1 = fmaf(WrP[i].y, v1.y, ar1);
                ar1 = fmaf(WrP[i].z, v1.z, ar1); ar1 = fmaf(WrP[i].w, v1.w, ar1);
                az1 = fmaf(WzP[i].x, v1.x, az1); az1 = fmaf(WzP[i].y, v1.y, az1);
                az1 = fmaf(WzP[i].z, v1.z, az1); az1 = fmaf(WzP[i].w, v1.w, az1);
                an1 = fmaf(WnP[i].x, v1.x, an1); an1 = fmaf(WnP[i].y, v1.y, an1);
                an1 = fmaf(WnP[i].z, v1.z, an1); an1 = fmaf(WnP[i].w, v1.w, an1);
            }
        }
        if (!k0) {
            ar0 += __shfl_xor(ar0, 16); ar0 += __shfl_xor(ar0, 32);
            az0 += __shfl_xor(az0, 16); az0 += __shfl_xor(az0, 32);
            an0 += __shfl_xor(an0, 16); an0 += __shfl_xor(an0, 32);
            sAr0 = ar0; sAz0 = az0; sAn0 = an0;
            while ((unsigned int)(pq0 >> 32) < tag0)
                pq0 = __hip_atomic_load(PDb0 + sl0 * 2 + q, __ATOMIC_RELAXED, __HIP_MEMORY_SCOPE_AGENT);
            float dns = sigm_((ownpd0 + __uint_as_float((unsigned int)pq0)) + lbv);
            u0 = dns * bu0; d0 = dns;
            sk0 = (u0 < 0.5f);
            ns0++; hp0 ^= 1;
        }
        if (!k1) {
            ar1 += __shfl_xor(ar1, 16); ar1 += __shfl_xor(ar1, 32);
            az1 += __shfl_xor(az1, 16); az1 += __shfl_xor(az1, 32);
            an1 += __shfl_xor(an1, 16); an1 += __shfl_xor(an1, 32);
            sAr1 = ar1; sAz1 = az1; sAn1 = an1;
            while ((unsigned int)(pq1 >> 32) < tag1)
                pq1 = __hip_atomic_load(PDb1 + sl1 * 2 + q, __ATOMIC_RELAXED, __HIP_MEMORY_SCOPE_AGENT);
            float dns = sigm_((ownpd1 + __uint_as_float((unsigned int)pq1)) + lbv);
            u1 = dns * bu1; d1 = dns;
            sk1 = (u1 < 0.5f);
            ns1++; hp1 ^= 1;
        }
        gir0 = nr0; giz0 = nz0; gin0 = ng0;
        gir1 = nr1; giz1 = nz1; gin1 = ng1;
    }
}

// ---------------------------------------------------------------------------
extern "C" void kernel_launch(void* const* d_in, const int* in_sizes, int n_in,
                              void* d_out, int out_size, void* d_ws, size_t ws_size,
                              hipStream_t stream)
{
    const float* x   = (const float*)d_in[0];  // (384,48,256)
    const float* hid = (const float*)d_in[1];  // (2,1,256)
    const float* wih = (const float*)d_in[2];  // (2,768,256)
    const float* whh = (const float*)d_in[3];  // (2,768,256)
    const float* bih = (const float*)d_in[4];  // (2,768)
    const float* bhh = (const float*)d_in[5];  // (2,768)
    const float* lw  = (const float*)d_in[6];  // (2,1,256)
    const float* lb  = (const float*)d_in[7];  // (2,1)
    float* out = (float*)d_out;

    float* ws = (float*)d_ws;
    float* GI = ws;                             // 18432*768 f32
    float* Y0 = GI + (size_t)18432 * 768;       // 18432*256 f32
    unsigned long long* XH0 = (unsigned long long*)(Y0 + (size_t)18432 * 256);
    unsigned long long* XH1 = XH0 + 48 * 512;   // 48 x [2][256] u64 per layer
    unsigned long long* PD0 = XH1 + 48 * 512;   // 48 x [2][2] u64 per layer
    unsigned long long* PD1 = PD0 + 48 * 4;

    float* OUTy = out;                          // (384,48,256)
    float* HS   = out + (size_t)18432 * 256;    // (2,48,256)
    float* TU   = HS + 2 * 48 * 256;            // (48, 768)

    // tags must start at 0 (< first wanted tag 1) regardless of workspace poison
    hipMemsetAsync(XH0, 0, (size_t)(48 * 512 * 2 + 48 * 4 * 2) * sizeof(unsigned long long), stream);

    dim3 ggrid(12, 144), gblk(256);
    gemm_nt<<<ggrid, gblk, 0, stream>>>(x, wih, bih, GI);
    rec_layer<<<48, 512, 0, stream>>>(GI, Y0, whh, bhh, lw, lb, hid, XH0, PD0, HS, TU);
    gemm_nt<<<ggrid, gblk, 0, stream>>>(Y0, wih + 196608, bih + 768, GI);
    rec_layer<<<48, 512, 0, stream>>>(GI, OUTy, whh + 196608, bhh + 768, lw + 256, lb + 1,
                                      hid + 256, XH1, PD1, HS + 12288, TU + 384);
}

// Round 5
// 3227.854 us; speedup vs baseline: 3.5054x; 3.5054x over previous
//
#include <hip/hip_runtime.h>
#include <stdint.h>

// SkipGRU: T=384, B=48, C=H=256, L=2.
// GEMM(gi = x@W_ih^T + b_ih) -> pairwise-WG recurrence -> GEMM -> recurrence.
//
// Recurrence: 2 WGs per batch element. Register-file capacity is the hard
// constraint: W_hh = 768 KB, per-CU RF = 512 KB, and __launch_bounds__(512,2)
// caps the unified VGPR+AGPR file at 256 regs/lane. Each WG holds half of W_hh
// (48 float4/lane = 192 regs) + ~64 state regs = exactly at the cap. (r4's
// J=2 batch interleave pushed past the cap -> W spilled to scratch -> 6x
// regression. Do NOT add per-step register state.)
//
// r5 changes vs r3 (928 us/layer):
//  1. LDS-only barriers: raw `s_waitcnt lgkmcnt(0); s_barrier` instead of
//     __syncthreads(). __syncthreads drains vmcnt(0), serializing Yout store
//     acks + XH publish acks + the in-flight GI HBM load (~900cy) into every
//     step, twice. All barrier-protected data here is LDS; XH/PD visibility
//     is enforced by tag-polling, not barriers.
//  2. GI(t+1) prefetch issued at the TOP of each step (was mid-step): full-step
//     latency cover.
//  3. L2 fast-path exchange: dual-publish tagged words (agent-scope copy for
//     cross-XCD correctness + plain store that lands in the writer's L2).
//     Paired WGs (blk, blk+48) land on the same XCD under %8 round-robin, so
//     an sc0 load (bypass L1, hit L2) sees the plain copy at ~250cy instead of
//     the ~700-1000cy LLC round trip of agent scope. Poll mix: 2 fast sc0
//     polls then 1 agent poll, so wrong-XCD placement or a stale L2 line can
//     never hang; tags make any winning path value-correct.
//
// Exchange protocol (r2, verified): (tag<<32)|float_bits, tag = ns+1,
// double-buffered by step parity. dns = sigm(pd_p + pd_q + lb) is commutative
// -> bit-identical skip trajectories in both WGs -> lockstep, no deadlock.
// Slot-reuse safety: a WG can only publish tag k+2 (same slot as k) after
// consuming the partner's k+1, which the partner publishes only after
// consuming our k -> overwrite-before-consume impossible.

#define T_STEPS 384
#define BATCH   48
#define HID     256

__device__ __forceinline__ float sigm_(float x) { return 1.f / (1.f + __expf(-x)); }
__device__ __forceinline__ float tanh_(float x) {
    float ax = fabsf(x);
    float e  = __expf(-2.f * ax);
    float r  = (1.f - e) / (1.f + e);
    return copysignf(r, x);
}

// barrier that waits only LDS ops (no vmcnt drain)
__device__ __forceinline__ void bar_lds() {
    asm volatile("s_waitcnt lgkmcnt(0)\n\ts_barrier" ::: "memory");
}

// sc0 load: bypass L1, serviced at L2 (same-XCD fast path for the exchange)
__device__ __forceinline__ unsigned long long ld_l2(const unsigned long long* p) {
    unsigned long long v;
    asm volatile("global_load_dwordx2 %0, %1, off sc0\n\ts_waitcnt vmcnt(0)"
                 : "=v"(v) : "v"(p) : "memory");
    return v;
}

// ---------------------------------------------------------------------------
// GEMM: O[m][n] = sum_k X[m][k] * W[n][k] + B[n];  M=18432, N=768, K=256.
// grid (12, 144), block 256. Tile 128(M) x 64(N), K-chunks of 32 staged in LDS.
// (unchanged; ~140 us each, not the current bottleneck)
// ---------------------------------------------------------------------------
__global__ __launch_bounds__(256, 2) void gemm_nt(const float* __restrict__ X,
                                                  const float* __restrict__ W,
                                                  const float* __restrict__ B,
                                                  float* __restrict__ O)
{
    __shared__ float As[32 * 140];
    __shared__ float Bs[32 * 68];

    const int tid = threadIdx.x;
    const int tx  = tid & 15;
    const int ty  = tid >> 4;
    const int n0  = blockIdx.x * 64;
    const int m0  = blockIdx.y * 128;

    float acc[8][4];
#pragma unroll
    for (int i = 0; i < 8; ++i)
#pragma unroll
        for (int j = 0; j < 4; ++j) acc[i][j] = 0.f;

    const float4 bias4 = *reinterpret_cast<const float4*>(B + n0 + tx * 4);

    for (int kc = 0; kc < 8; ++kc) {
        const int k0 = kc * 32;
        float4 a[4], bb[2];
#pragma unroll
        for (int j = 0; j < 4; ++j) {
            int f = tid + 256 * j, r = f >> 3, cq = f & 7;
            a[j] = *reinterpret_cast<const float4*>(X + (size_t)(m0 + r) * 256 + k0 + cq * 4);
        }
#pragma unroll
        for (int j = 0; j < 2; ++j) {
            int f = tid + 256 * j, r = f >> 3, cq = f & 7;
            bb[j] = *reinterpret_cast<const float4*>(W + (size_t)(n0 + r) * 256 + k0 + cq * 4);
        }
        __syncthreads();
#pragma unroll
        for (int j = 0; j < 4; ++j) {
            int f = tid + 256 * j, r = f >> 3, cq = f & 7;
            As[(cq * 4 + 0) * 140 + r] = a[j].x;
            As[(cq * 4 + 1) * 140 + r] = a[j].y;
            As[(cq * 4 + 2) * 140 + r] = a[j].z;
            As[(cq * 4 + 3) * 140 + r] = a[j].w;
        }
#pragma unroll
        for (int j = 0; j < 2; ++j) {
            int f = tid + 256 * j, r = f >> 3, cq = f & 7;
            Bs[(cq * 4 + 0) * 68 + r] = bb[j].x;
            Bs[(cq * 4 + 1) * 68 + r] = bb[j].y;
            Bs[(cq * 4 + 2) * 68 + r] = bb[j].z;
            Bs[(cq * 4 + 3) * 68 + r] = bb[j].w;
        }
        __syncthreads();
#pragma unroll 8
        for (int kk = 0; kk < 32; ++kk) {
            float4 av0 = *reinterpret_cast<const float4*>(As + kk * 140 + ty * 8);
            float4 av1 = *reinterpret_cast<const float4*>(As + kk * 140 + ty * 8 + 4);
            float4 bv  = *reinterpret_cast<const float4*>(Bs + kk * 68 + tx * 4);
            float am[8] = {av0.x, av0.y, av0.z, av0.w, av1.x, av1.y, av1.z, av1.w};
            float bn[4] = {bv.x, bv.y, bv.z, bv.w};
#pragma unroll
            for (int i = 0; i < 8; ++i)
#pragma unroll
                for (int j = 0; j < 4; ++j) acc[i][j] = fmaf(am[i], bn[j], acc[i][j]);
        }
    }
#pragma unroll
    for (int i = 0; i < 8; ++i) {
        int row = m0 + ty * 8 + i;
        float4 o;
        o.x = acc[i][0] + bias4.x;
        o.y = acc[i][1] + bias4.y;
        o.z = acc[i][2] + bias4.z;
        o.w = acc[i][3] + bias4.w;
        *reinterpret_cast<float4*>(O + (size_t)row * 768 + n0 + tx * 4) = o;
    }
}

// ---------------------------------------------------------------------------
// Recurrence. grid = 96 (p = blk/48, b = blk%48), block 512.
// WG p owns h-columns [p*128, p*128+128) and W_hh rows {c, 256+c, 512+c}.
// Wave w (0..7), g = lane&15 -> column c = p*128 + w*16 + g.
// Sub s = lane>>4: own k-slice [p*128+s*32,+32), partner [q*128+s*32,+32).
// hbuf: double-buffered (parity hp) x 4 shifted copies (stride 264) ->
// conflict-free broadcast b128 reads.
// ---------------------------------------------------------------------------
__global__ __launch_bounds__(512, 2) void rec_layer(
    const float* __restrict__ GI, float* __restrict__ Yout,
    const float* __restrict__ whh, const float* __restrict__ bhh,
    const float* __restrict__ lwl, const float* __restrict__ lbl,
    const float* __restrict__ hid,
    unsigned long long* XH, unsigned long long* XF,
    unsigned long long* PD, unsigned long long* PF,
    float* __restrict__ hsout, float* __restrict__ tuout)
{
    __shared__ float hbuf[2112];   // 2 parities x (4 copies x 264)
    __shared__ float pdw[2][8];

    const int tid  = threadIdx.x;
    const int lane = tid & 63;
    const int w    = tid >> 6;
    const int g    = lane & 15;
    const int s    = lane >> 4;
    const int b    = blockIdx.x % 48;
    const int p    = blockIdx.x / 48;   // pair (i, i+48): same XCD under %8 round-robin
    const int q    = 1 - p;
    const int c    = p * 128 + w * 16 + g;

    // W_hh fragments (own-k and partner-k sub-slices); 48 float4/lane
    float4 WrO[8], WzO[8], WnO[8], WrP[8], WzP[8], WnP[8];
    {
        const size_t rR = (size_t)c * 256;
        const size_t rZ = (size_t)(256 + c) * 256;
        const size_t rN = (size_t)(512 + c) * 256;
        const int ko = p * 128 + s * 32;
        const int kq = q * 128 + s * 32;
        const float4* a  = reinterpret_cast<const float4*>(whh + rR + ko);
        const float4* bv = reinterpret_cast<const float4*>(whh + rZ + ko);
        const float4* cv = reinterpret_cast<const float4*>(whh + rN + ko);
        const float4* d4 = reinterpret_cast<const float4*>(whh + rR + kq);
        const float4* e4 = reinterpret_cast<const float4*>(whh + rZ + kq);
        const float4* f4 = reinterpret_cast<const float4*>(whh + rN + kq);
#pragma unroll
        for (int i = 0; i < 8; ++i) {
            WrO[i] = a[i];  WzO[i] = bv[i]; WnO[i] = cv[i];
            WrP[i] = d4[i]; WzP[i] = e4[i]; WnP[i] = f4[i];
        }
    }

    const float bhr = bhh[c], bhz = bhh[256 + c], bhn = bhh[512 + c];
    const float lwc = lwl[c];
    const float lbv = lbl[0];

    if (tid < 256) {
        float v = hid[tid];
        hbuf[tid] = v; hbuf[264 + tid] = v; hbuf[528 + tid] = v; hbuf[792 + tid] = v;
    }
    bar_lds();

    // prologue: gi(0) + stashed A(0) = W_hh . h(0)
    float gir, giz, gin;
    {
        const size_t g0 = (size_t)b * 768 + c;
        gir = GI[g0]; giz = GI[g0 + 256]; gin = GI[g0 + 512];
    }
    float sAr, sAz, sAn;
    {
        float ar = 0.f, az = 0.f, an = 0.f;
        const float4* ho = reinterpret_cast<const float4*>(hbuf + s * 264 + p * 128 + s * 32);
        const float4* hq = reinterpret_cast<const float4*>(hbuf + s * 264 + q * 128 + s * 32);
#pragma unroll
        for (int i = 0; i < 8; ++i) {
            float4 hv = ho[i];
            ar = fmaf(WrO[i].x, hv.x, ar); ar = fmaf(WrO[i].y, hv.y, ar);
            ar = fmaf(WrO[i].z, hv.z, ar); ar = fmaf(WrO[i].w, hv.w, ar);
            az = fmaf(WzO[i].x, hv.x, az); az = fmaf(WzO[i].y, hv.y, az);
            az = fmaf(WzO[i].z, hv.z, az); az = fmaf(WzO[i].w, hv.w, az);
            an = fmaf(WnO[i].x, hv.x, an); an = fmaf(WnO[i].y, hv.y, an);
            an = fmaf(WnO[i].z, hv.z, an); an = fmaf(WnO[i].w, hv.w, an);
        }
#pragma unroll
        for (int i = 0; i < 8; ++i) {
            float4 hv = hq[i];
            ar = fmaf(WrP[i].x, hv.x, ar); ar = fmaf(WrP[i].y, hv.y, ar);
            ar = fmaf(WrP[i].z, hv.z, ar); ar = fmaf(WrP[i].w, hv.w, ar);
            az = fmaf(WzP[i].x, hv.x, az); az = fmaf(WzP[i].y, hv.y, az);
            az = fmaf(WzP[i].z, hv.z, az); az = fmaf(WzP[i].w, hv.w, az);
            an = fmaf(WnP[i].x, hv.x, an); an = fmaf(WnP[i].y, hv.y, an);
            an = fmaf(WnP[i].z, hv.z, an); an = fmaf(WnP[i].w, hv.w, an);
        }
        ar += __shfl_xor(ar, 16); ar += __shfl_xor(ar, 32);
        az += __shfl_xor(az, 16); az += __shfl_xor(az, 32);
        an += __shfl_xor(an, 16); an += __shfl_xor(an, 32);
        sAr = ar; sAz = az; sAn = an;
    }

    float u = 1.f, d = 0.f;
    bool  skip = false;
    int   ns = 0;   // non-skip step counter; tag = ns+1, slot = ns&1
    int   hp = 0;   // hbuf parity

    unsigned long long* XHb = XH + b * 512;
    unsigned long long* XFb = XF + b * 512;
    unsigned long long* PDb = PD + b * 4;
    unsigned long long* PFb = PF + b * 4;

    for (int t = 0; t < T_STEPS; ++t) {
        const float bu  = rintf(u);        // jnp.round == RNE
        const float obu = 1.f - bu;
        const size_t yrow = ((size_t)t * 48 + b) * 256;
        const int tp = (t < T_STEPS - 1) ? t + 1 : t;
        const size_t gpb = ((size_t)tp * 48 + b) * 768 + c;

        // gi(t+1) prefetch at step TOP: full-step latency cover
        float pr = GI[gpb], pz = GI[gpb + 256], pn = GI[gpb + 512];

        if (skip) {
            // new_h = h*(1-bu); new_u = clip(u+d,0,1)*(1-bu); d unchanged; no comm.
            float* hb = hbuf + hp * 1056;
            if (s == 0) {
                float hcv = hb[c];
                float nh  = hcv * obu;
                if (bu != 0.f) { hb[c] = nh; hb[264 + c] = nh; hb[528 + c] = nh; hb[792 + c] = nh; }
                Yout[yrow + c] = nh;
                if (t == T_STEPS - 1) hsout[b * 256 + c] = nh;
            }
            if (bu != 0.f) { sAr = 0.f; sAz = 0.f; sAn = 0.f; }  // h zeroed -> A zeroed
            if (p == 0 && tid == 0) tuout[b * 768 + t] = bu;
            u    = fminf(fmaxf(u + d, 0.f), 1.f) * obu;
            skip = (u < 0.5f);
            bar_lds();
        } else {
            const int sl = ns & 1;
            const unsigned int tag = (unsigned int)ns + 1u;

            // gates from stashed A(t) + prefetched gi(t)
            float hcv = hbuf[hp * 1056 + s * 264 + c];  // old h[c]
            float rr  = sigm_(gir + sAr + bhr);
            float zz  = sigm_(giz + sAz + bhz);
            float tn  = tanh_(gin + rr * (sAn + bhn));
            float nh  = ((1.f - zz) * tn + zz * hcv) * bu;  // h_ns == new_h (not skipping)
            float pdv = nh * lwc;

            float* hbn = hbuf + (hp ^ 1) * 1056;   // next-parity buffer (no WAR hazard)
            if (s == 0) {
                unsigned long long pk = ((unsigned long long)tag << 32) |
                                        (unsigned long long)__float_as_uint(nh);
                __hip_atomic_store(XHb + sl * 256 + c, pk, __ATOMIC_RELAXED, __HIP_MEMORY_SCOPE_AGENT);
                *(volatile unsigned long long*)(XFb + sl * 256 + c) = pk;  // L2 fast copy
                hbn[c] = nh; hbn[264 + c] = nh; hbn[528 + c] = nh; hbn[792 + c] = nh;
                Yout[yrow + c] = nh;
                if (t == T_STEPS - 1) hsout[b * 256 + c] = nh;
            }
            // exact wave butterfly: 4 identical copies per column -> 4*S, *0.25 exact
            pdv += __shfl_xor(pdv, 1);  pdv += __shfl_xor(pdv, 2);  pdv += __shfl_xor(pdv, 4);
            pdv += __shfl_xor(pdv, 8);  pdv += __shfl_xor(pdv, 16); pdv += __shfl_xor(pdv, 32);
            pdv *= 0.25f;
            if (lane == 0) pdw[sl][w] = pdv;
            if (p == 0 && tid == 0) tuout[b * 768 + t] = bu;

            // early partner-h poll issue: rides in flight across the barrier
            unsigned long long pk0 = 0;
            if (tid < 128)
                pk0 = __hip_atomic_load(XHb + sl * 256 + q * 128 + tid, __ATOMIC_RELAXED, __HIP_MEMORY_SCOPE_AGENT);

            bar_lds();  // B1 (LDS only): own-half hbn + pdw visible WG-wide

            float ownpd = ((pdw[sl][0] + pdw[sl][1]) + (pdw[sl][2] + pdw[sl][3]))
                        + ((pdw[sl][4] + pdw[sl][5]) + (pdw[sl][6] + pdw[sl][7]));
            if (tid == 0) {
                unsigned long long pk = ((unsigned long long)tag << 32) |
                                        (unsigned long long)__float_as_uint(ownpd);
                __hip_atomic_store(PDb + sl * 2 + p, pk, __ATOMIC_RELAXED, __HIP_MEMORY_SCOPE_AGENT);
                *(volatile unsigned long long*)(PFb + sl * 2 + p) = pk;
            }
            // early partner-pd poll issue (uniform address -> one transaction)
            unsigned long long pkq = __hip_atomic_load(PDb + sl * 2 + q, __ATOMIC_RELAXED, __HIP_MEMORY_SCOPE_AGENT);

            // own-half partial of A(t+1) (speculative; exact under skip rules)
            float ar = 0.f, az = 0.f, an = 0.f;
            {
                const float4* ho = reinterpret_cast<const float4*>(hbn + s * 264 + p * 128 + s * 32);
#pragma unroll
                for (int i = 0; i < 8; ++i) {
                    float4 hv = ho[i];
                    ar = fmaf(WrO[i].x, hv.x, ar); ar = fmaf(WrO[i].y, hv.y, ar);
                    ar = fmaf(WrO[i].z, hv.z, ar); ar = fmaf(WrO[i].w, hv.w, ar);
                    az = fmaf(WzO[i].x, hv.x, az); az = fmaf(WzO[i].y, hv.y, az);
                    az = fmaf(WzO[i].z, hv.z, az); az = fmaf(WzO[i].w, hv.w, az);
                    an = fmaf(WnO[i].x, hv.x, an); an = fmaf(WnO[i].y, hv.y, an);
                    an = fmaf(WnO[i].z, hv.z, an); an = fmaf(WnO[i].w, hv.w, an);
                }
            }
            // complete partner-h poll: 2 fast L2 (sc0) polls, then 1 agent poll
            if (tid < 128) {
                const int qc = q * 128 + tid;
                const unsigned long long* fap = XFb + sl * 256 + qc;
                const unsigned long long* slp = XHb + sl * 256 + qc;
                while ((unsigned int)(pk0 >> 32) < tag) {
                    pk0 = ld_l2(fap);
                    if ((unsigned int)(pk0 >> 32) >= tag) break;
                    pk0 = ld_l2(fap);
                    if ((unsigned int)(pk0 >> 32) >= tag) break;
                    pk0 = __hip_atomic_load(slp, __ATOMIC_RELAXED, __HIP_MEMORY_SCOPE_AGENT);
                }
                float v = __uint_as_float((unsigned int)pk0);
                hbn[qc] = v; hbn[264 + qc] = v; hbn[528 + qc] = v; hbn[792 + qc] = v;
            }
            bar_lds();  // B2 (LDS only): partner half of hbn in place

            // partner-half partial of A(t+1)
            {
                const float4* hq = reinterpret_cast<const float4*>(hbn + s * 264 + q * 128 + s * 32);
#pragma unroll
                for (int i = 0; i < 8; ++i) {
                    float4 hv = hq[i];
                    ar = fmaf(WrP[i].x, hv.x, ar); ar = fmaf(WrP[i].y, hv.y, ar);
                    ar = fmaf(WrP[i].z, hv.z, ar); ar = fmaf(WrP[i].w, hv.w, ar);
                    az = fmaf(WzP[i].x, hv.x, az); az = fmaf(WzP[i].y, hv.y, az);
                    az = fmaf(WzP[i].z, hv.z, az); az = fmaf(WzP[i].w, hv.w, az);
                    an = fmaf(WnP[i].x, hv.x, an); an = fmaf(WnP[i].y, hv.y, an);
                    an = fmaf(WnP[i].z, hv.z, an); an = fmaf(WnP[i].w, hv.w, an);
                }
            }
            ar += __shfl_xor(ar, 16); ar += __shfl_xor(ar, 32);
            az += __shfl_xor(az, 16); az += __shfl_xor(az, 32);
            an += __shfl_xor(an, 16); an += __shfl_xor(an, 32);
            sAr = ar; sAz = az; sAn = an;

            // complete partner-pd poll (same fast/agent mix)
            {
                const unsigned long long* fap = PFb + sl * 2 + q;
                const unsigned long long* slp = PDb + sl * 2 + q;
                while ((unsigned int)(pkq >> 32) < tag) {
                    pkq = ld_l2(fap);
                    if ((unsigned int)(pkq >> 32) >= tag) break;
                    pkq = ld_l2(fap);
                    if ((unsigned int)(pkq >> 32) >= tag) break;
                    pkq = __hip_atomic_load(slp, __ATOMIC_RELAXED, __HIP_MEMORY_SCOPE_AGENT);
                }
            }
            const float pdq = __uint_as_float((unsigned int)pkq);

            float dns = sigm_((ownpd + pdq) + lbv);  // commutative -> bit-identical in both WGs
            u = dns * bu; d = dns;
            skip = (u < 0.5f);
            ns++; hp ^= 1;
        }
        gir = pr; giz = pz; gin = pn;
    }
}

// ---------------------------------------------------------------------------
extern "C" void kernel_launch(void* const* d_in, const int* in_sizes, int n_in,
                              void* d_out, int out_size, void* d_ws, size_t ws_size,
                              hipStream_t stream)
{
    const float* x   = (const float*)d_in[0];  // (384,48,256)
    const float* hid = (const float*)d_in[1];  // (2,1,256)
    const float* wih = (const float*)d_in[2];  // (2,768,256)
    const float* whh = (const float*)d_in[3];  // (2,768,256)
    const float* bih = (const float*)d_in[4];  // (2,768)
    const float* bhh = (const float*)d_in[5];  // (2,768)
    const float* lw  = (const float*)d_in[6];  // (2,1,256)
    const float* lb  = (const float*)d_in[7];  // (2,1)
    float* out = (float*)d_out;

    float* ws = (float*)d_ws;
    float* GI = ws;                             // 18432*768 f32
    float* Y0 = GI + (size_t)18432 * 768;       // 18432*256 f32
    unsigned long long* XH0 = (unsigned long long*)(Y0 + (size_t)18432 * 256);
    unsigned long long* XH1 = XH0 + 48 * 512;   // agent copies, 48 x [2][256] u64 / layer
    unsigned long long* XF0 = XH1 + 48 * 512;   // L2 fast copies
    unsigned long long* XF1 = XF0 + 48 * 512;
    unsigned long long* PD0 = XF1 + 48 * 512;   // agent pd, 48 x [2][2] u64 / layer
    unsigned long long* PD1 = PD0 + 192;
    unsigned long long* PF0 = PD1 + 192;        // L2 fast pd
    unsigned long long* PF1 = PF0 + 192;

    float* OUTy = out;                          // (384,48,256)
    float* HS   = out + (size_t)18432 * 256;    // (2,48,256)
    float* TU   = HS + 2 * 48 * 256;            // (48, 768)

    // tags must start at 0 (< first wanted tag 1) regardless of workspace poison:
    // XH0..PF1 contiguous = 4*(48*512) + 4*192 u64 = 99072 u64
    hipMemsetAsync(XH0, 0, (size_t)99072 * sizeof(unsigned long long), stream);

    dim3 ggrid(12, 144), gblk(256);
    gemm_nt<<<ggrid, gblk, 0, stream>>>(x, wih, bih, GI);
    rec_layer<<<96, 512, 0, stream>>>(GI, Y0, whh, bhh, lw, lb, hid,
                                      XH0, XF0, PD0, PF0, HS, TU);
    gemm_nt<<<ggrid, gblk, 0, stream>>>(Y0, wih + 196608, bih + 768, GI);
    rec_layer<<<96, 512, 0, stream>>>(GI, OUTy, whh + 196608, bhh + 768, lw + 256, lb + 1,
                                      hid + 256, XH1, XF1, PD1, PF1, HS + 12288, TU + 384);
}

// Round 6
// 2781.663 us; speedup vs baseline: 4.0677x; 1.1604x over previous
//
#include <hip/hip_runtime.h>
#include <stdint.h>

// SkipGRU: T=384, B=48, C=H=256, L=2.
// GEMM(gi = x@W_ih^T + b_ih) -> pairwise-WG recurrence -> GEMM -> recurrence.
//
// Recurrence: 2 WGs per batch element. Register-file capacity is the hard
// constraint: W_hh = 768 KB, per-CU RF = 512 KB; each WG holds half of W_hh in
// registers (48 float4/lane @ 512 threads = 192 regs, cap is 256 at 2 blocks/
// CU). r4's J=2 batch interleave exceeded the cap -> scratch spill -> 6x
// regression. r5's inline-asm sc0 poll carried s_waitcnt vmcnt(0) -> drained
// the GI prefetch on every retry -> 1.6x regression. Lessons: no extra
// per-step register state; polls must be COMPILER-TRACKED loads.
//
// r6 = r3 skeleton (928 us/layer, verified) + clean subset:
//  1. LDS-only barriers (s_waitcnt lgkmcnt(0); s_barrier): __syncthreads
//     drains vmcnt(0), serializing Yout/XH store acks + in-flight GI loads
//     into every step twice. All barrier-protected data is LDS; XH visibility
//     is carried by the tag packed in the same 8B word.
//  2. Early partner poll issued at step TOP, BEFORE the GI prefetch: with
//     in-order vmcnt decrement, checking pk0 waits only the poll load and
//     leaves the GI loads in flight (retries do drain GI, but by then GI has
//     had the whole phase to complete).
//  3. PD exchange ELIMINATED: the 128 receiving lanes recompute the partner's
//     pd-half locally from the received h values, bit-exactly replicating the
//     partner's reduction tree (xor1/2/4/8 butterfly == partner's pdw[w];
//     then the identical 8-term tree). dns = sigm((S_own+S_partner)+lb) is
//     commutative -> bit-identical in both WGs -> lockstep preserved. This
//     removes the tail-of-step pd poll (a bare LLC round trip).
//
// Exchange protocol (r2, verified): (tag<<32)|float_bits, tag = ns+1, slots
// double-buffered by parity; overwrite-before-consume impossible (publish of
// tag k+2 requires consuming k+1, which required partner consuming k).

#define T_STEPS 384
#define BATCH   48
#define HID     256

__device__ __forceinline__ float sigm_(float x) { return 1.f / (1.f + __expf(-x)); }
__device__ __forceinline__ float tanh_(float x) {
    float ax = fabsf(x);
    float e  = __expf(-2.f * ax);
    float r  = (1.f - e) / (1.f + e);
    return copysignf(r, x);
}

// barrier that waits only LDS ops (no vmcnt drain)
__device__ __forceinline__ void bar_lds() {
    asm volatile("s_waitcnt lgkmcnt(0)\n\ts_barrier" ::: "memory");
}

// ---------------------------------------------------------------------------
// GEMM: O[m][n] = sum_k X[m][k] * W[n][k] + B[n];  M=18432, N=768, K=256.
// grid (12, 144), block 256. Tile 128(M) x 64(N), K-chunks of 32 staged in LDS.
// (unchanged; ~140 us each, not the current bottleneck)
// ---------------------------------------------------------------------------
__global__ __launch_bounds__(256, 2) void gemm_nt(const float* __restrict__ X,
                                                  const float* __restrict__ W,
                                                  const float* __restrict__ B,
                                                  float* __restrict__ O)
{
    __shared__ float As[32 * 140];
    __shared__ float Bs[32 * 68];

    const int tid = threadIdx.x;
    const int tx  = tid & 15;
    const int ty  = tid >> 4;
    const int n0  = blockIdx.x * 64;
    const int m0  = blockIdx.y * 128;

    float acc[8][4];
#pragma unroll
    for (int i = 0; i < 8; ++i)
#pragma unroll
        for (int j = 0; j < 4; ++j) acc[i][j] = 0.f;

    const float4 bias4 = *reinterpret_cast<const float4*>(B + n0 + tx * 4);

    for (int kc = 0; kc < 8; ++kc) {
        const int k0 = kc * 32;
        float4 a[4], bb[2];
#pragma unroll
        for (int j = 0; j < 4; ++j) {
            int f = tid + 256 * j, r = f >> 3, cq = f & 7;
            a[j] = *reinterpret_cast<const float4*>(X + (size_t)(m0 + r) * 256 + k0 + cq * 4);
        }
#pragma unroll
        for (int j = 0; j < 2; ++j) {
            int f = tid + 256 * j, r = f >> 3, cq = f & 7;
            bb[j] = *reinterpret_cast<const float4*>(W + (size_t)(n0 + r) * 256 + k0 + cq * 4);
        }
        __syncthreads();
#pragma unroll
        for (int j = 0; j < 4; ++j) {
            int f = tid + 256 * j, r = f >> 3, cq = f & 7;
            As[(cq * 4 + 0) * 140 + r] = a[j].x;
            As[(cq * 4 + 1) * 140 + r] = a[j].y;
            As[(cq * 4 + 2) * 140 + r] = a[j].z;
            As[(cq * 4 + 3) * 140 + r] = a[j].w;
        }
#pragma unroll
        for (int j = 0; j < 2; ++j) {
            int f = tid + 256 * j, r = f >> 3, cq = f & 7;
            Bs[(cq * 4 + 0) * 68 + r] = bb[j].x;
            Bs[(cq * 4 + 1) * 68 + r] = bb[j].y;
            Bs[(cq * 4 + 2) * 68 + r] = bb[j].z;
            Bs[(cq * 4 + 3) * 68 + r] = bb[j].w;
        }
        __syncthreads();
#pragma unroll 8
        for (int kk = 0; kk < 32; ++kk) {
            float4 av0 = *reinterpret_cast<const float4*>(As + kk * 140 + ty * 8);
            float4 av1 = *reinterpret_cast<const float4*>(As + kk * 140 + ty * 8 + 4);
            float4 bv  = *reinterpret_cast<const float4*>(Bs + kk * 68 + tx * 4);
            float am[8] = {av0.x, av0.y, av0.z, av0.w, av1.x, av1.y, av1.z, av1.w};
            float bn[4] = {bv.x, bv.y, bv.z, bv.w};
#pragma unroll
            for (int i = 0; i < 8; ++i)
#pragma unroll
                for (int j = 0; j < 4; ++j) acc[i][j] = fmaf(am[i], bn[j], acc[i][j]);
        }
    }
#pragma unroll
    for (int i = 0; i < 8; ++i) {
        int row = m0 + ty * 8 + i;
        float4 o;
        o.x = acc[i][0] + bias4.x;
        o.y = acc[i][1] + bias4.y;
        o.z = acc[i][2] + bias4.z;
        o.w = acc[i][3] + bias4.w;
        *reinterpret_cast<float4*>(O + (size_t)row * 768 + n0 + tx * 4) = o;
    }
}

// ---------------------------------------------------------------------------
// Recurrence. grid = 96 (p = blk/48, b = blk%48), block 512.
// WG p owns h-columns [p*128, p*128+128) and W_hh rows {c, 256+c, 512+c}.
// Wave w (0..7), g = lane&15 -> column c = p*128 + w*16 + g.
// Sub s = lane>>4: own k-slice [p*128+s*32,+32), partner [q*128+s*32,+32).
// hbuf: double-buffered (parity hp) x 4 shifted copies (stride 264) ->
// conflict-free broadcast b128 reads.
// ---------------------------------------------------------------------------
__global__ __launch_bounds__(512, 2) void rec_layer(
    const float* __restrict__ GI, float* __restrict__ Yout,
    const float* __restrict__ whh, const float* __restrict__ bhh,
    const float* __restrict__ lwl, const float* __restrict__ lbl,
    const float* __restrict__ hid,
    unsigned long long* XH,
    float* __restrict__ hsout, float* __restrict__ tuout)
{
    __shared__ float hbuf[2112];   // 2 parities x (4 copies x 264)
    __shared__ float pdw[8];       // own-half per-wave partials
    __shared__ float qpd[8];       // partner-half per-group partials (recomputed)

    const int tid  = threadIdx.x;
    const int lane = tid & 63;
    const int w    = tid >> 6;
    const int g    = lane & 15;
    const int s    = lane >> 4;
    const int b    = blockIdx.x % 48;
    const int p    = blockIdx.x / 48;   // pair (i, i+48): same XCD under %8 round-robin
    const int q    = 1 - p;
    const int c    = p * 128 + w * 16 + g;

    // W_hh fragments (own-k and partner-k sub-slices); 48 float4/lane
    float4 WrO[8], WzO[8], WnO[8], WrP[8], WzP[8], WnP[8];
    {
        const size_t rR = (size_t)c * 256;
        const size_t rZ = (size_t)(256 + c) * 256;
        const size_t rN = (size_t)(512 + c) * 256;
        const int ko = p * 128 + s * 32;
        const int kq = q * 128 + s * 32;
        const float4* a  = reinterpret_cast<const float4*>(whh + rR + ko);
        const float4* bv = reinterpret_cast<const float4*>(whh + rZ + ko);
        const float4* cv = reinterpret_cast<const float4*>(whh + rN + ko);
        const float4* d4 = reinterpret_cast<const float4*>(whh + rR + kq);
        const float4* e4 = reinterpret_cast<const float4*>(whh + rZ + kq);
        const float4* f4 = reinterpret_cast<const float4*>(whh + rN + kq);
#pragma unroll
        for (int i = 0; i < 8; ++i) {
            WrO[i] = a[i];  WzO[i] = bv[i]; WnO[i] = cv[i];
            WrP[i] = d4[i]; WzP[i] = e4[i]; WnP[i] = f4[i];
        }
    }

    const float bhr = bhh[c], bhz = bhh[256 + c], bhn = bhh[512 + c];
    const float lwc = lwl[c];
    const float lbv = lbl[0];
    // lw for the partner column this lane will receive (tid<128 only)
    const float lwq = (tid < 128) ? lwl[q * 128 + tid] : 0.f;

    if (tid < 256) {
        float v = hid[tid];
        hbuf[tid] = v; hbuf[264 + tid] = v; hbuf[528 + tid] = v; hbuf[792 + tid] = v;
    }
    bar_lds();

    // prologue: gi(0) + stashed A(0) = W_hh . h(0)
    float gir, giz, gin;
    {
        const size_t g0 = (size_t)b * 768 + c;
        gir = GI[g0]; giz = GI[g0 + 256]; gin = GI[g0 + 512];
    }
    float sAr, sAz, sAn;
    {
        float ar = 0.f, az = 0.f, an = 0.f;
        const float4* ho = reinterpret_cast<const float4*>(hbuf + s * 264 + p * 128 + s * 32);
        const float4* hq = reinterpret_cast<const float4*>(hbuf + s * 264 + q * 128 + s * 32);
#pragma unroll
        for (int i = 0; i < 8; ++i) {
            float4 hv = ho[i];
            ar = fmaf(WrO[i].x, hv.x, ar); ar = fmaf(WrO[i].y, hv.y, ar);
            ar = fmaf(WrO[i].z, hv.z, ar); ar = fmaf(WrO[i].w, hv.w, ar);
            az = fmaf(WzO[i].x, hv.x, az); az = fmaf(WzO[i].y, hv.y, az);
            az = fmaf(WzO[i].z, hv.z, az); az = fmaf(WzO[i].w, hv.w, az);
            an = fmaf(WnO[i].x, hv.x, an); an = fmaf(WnO[i].y, hv.y, an);
            an = fmaf(WnO[i].z, hv.z, an); an = fmaf(WnO[i].w, hv.w, an);
        }
#pragma unroll
        for (int i = 0; i < 8; ++i) {
            float4 hv = hq[i];
            ar = fmaf(WrP[i].x, hv.x, ar); ar = fmaf(WrP[i].y, hv.y, ar);
            ar = fmaf(WrP[i].z, hv.z, ar); ar = fmaf(WrP[i].w, hv.w, ar);
            az = fmaf(WzP[i].x, hv.x, az); az = fmaf(WzP[i].y, hv.y, az);
            az = fmaf(WzP[i].z, hv.z, az); az = fmaf(WzP[i].w, hv.w, az);
            an = fmaf(WnP[i].x, hv.x, an); an = fmaf(WnP[i].y, hv.y, an);
            an = fmaf(WnP[i].z, hv.z, an); an = fmaf(WnP[i].w, hv.w, an);
        }
        ar += __shfl_xor(ar, 16); ar += __shfl_xor(ar, 32);
        az += __shfl_xor(az, 16); az += __shfl_xor(az, 32);
        an += __shfl_xor(an, 16); an += __shfl_xor(an, 32);
        sAr = ar; sAz = az; sAn = an;
    }

    float u = 1.f, d = 0.f;
    bool  skip = false;
    int   ns = 0;   // non-skip step counter; tag = ns+1, slot = ns&1
    int   hp = 0;   // hbuf parity

    unsigned long long* XHb = XH + b * 512;

    for (int t = 0; t < T_STEPS; ++t) {
        const float bu  = rintf(u);        // jnp.round == RNE
        const float obu = 1.f - bu;
        const size_t yrow = ((size_t)t * 48 + b) * 256;
        const int tp = (t < T_STEPS - 1) ? t + 1 : t;
        const size_t gpb = ((size_t)tp * 48 + b) * 768 + c;

        if (skip) {
            // gi(t+1) prefetch; no comm this step.
            float pr = GI[gpb], pz = GI[gpb + 256], pn = GI[gpb + 512];
            float* hb = hbuf + hp * 1056;
            if (s == 0) {
                float hcv = hb[c];
                float nh  = hcv * obu;
                if (bu != 0.f) { hb[c] = nh; hb[264 + c] = nh; hb[528 + c] = nh; hb[792 + c] = nh; }
                Yout[yrow + c] = nh;
                if (t == T_STEPS - 1) hsout[b * 256 + c] = nh;
            }
            if (bu != 0.f) { sAr = 0.f; sAz = 0.f; sAn = 0.f; }  // h zeroed -> A zeroed
            if (p == 0 && tid == 0) tuout[b * 768 + t] = bu;
            u    = fminf(fmaxf(u + d, 0.f), 1.f) * obu;
            skip = (u < 0.5f);
            bar_lds();
            gir = pr; giz = pz; gin = pn;
        } else {
            const int sl = ns & 1;
            const unsigned int tag = (unsigned int)ns + 1u;

            // earliest possible poll issue (oldest outstanding load -> checking
            // it later does NOT force draining the newer GI prefetch)
            unsigned long long pk0 = 0;
            if (tid < 128)
                pk0 = __hip_atomic_load(XHb + sl * 256 + q * 128 + tid, __ATOMIC_RELAXED, __HIP_MEMORY_SCOPE_AGENT);
            // gi(t+1) prefetch: full-step latency cover
            float pr = GI[gpb], pz = GI[gpb + 256], pn = GI[gpb + 512];

            // gates from stashed A(t) + prefetched gi(t)
            float hcv = hbuf[hp * 1056 + s * 264 + c];  // old h[c]
            float rr  = sigm_(gir + sAr + bhr);
            float zz  = sigm_(giz + sAz + bhz);
            float tn  = tanh_(gin + rr * (sAn + bhn));
            float nh  = ((1.f - zz) * tn + zz * hcv) * bu;  // h_ns == new_h (not skipping)
            float pdv = nh * lwc;

            float* hbn = hbuf + (hp ^ 1) * 1056;   // next-parity buffer (no WAR hazard)
            if (s == 0) {
                unsigned long long pk = ((unsigned long long)tag << 32) |
                                        (unsigned long long)__float_as_uint(nh);
                __hip_atomic_store(XHb + sl * 256 + c, pk, __ATOMIC_RELAXED, __HIP_MEMORY_SCOPE_AGENT);
                hbn[c] = nh; hbn[264 + c] = nh; hbn[528 + c] = nh; hbn[792 + c] = nh;
                Yout[yrow + c] = nh;
                if (t == T_STEPS - 1) hsout[b * 256 + c] = nh;
            }
            // exact wave butterfly: 4 identical copies per column -> 4*S, *0.25 exact
            pdv += __shfl_xor(pdv, 1);  pdv += __shfl_xor(pdv, 2);  pdv += __shfl_xor(pdv, 4);
            pdv += __shfl_xor(pdv, 8);  pdv += __shfl_xor(pdv, 16); pdv += __shfl_xor(pdv, 32);
            pdv *= 0.25f;
            if (lane == 0) pdw[w] = pdv;
            if (p == 0 && tid == 0) tuout[b * 768 + t] = bu;

            bar_lds();  // B1 (LDS only): own-half hbn + pdw visible WG-wide

            float ownpd = ((pdw[0] + pdw[1]) + (pdw[2] + pdw[3]))
                        + ((pdw[4] + pdw[5]) + (pdw[6] + pdw[7]));

            // own-half partial of A(t+1) (speculative; exact under skip rules)
            // overlaps the partner-h flight
            float ar = 0.f, az = 0.f, an = 0.f;
            {
                const float4* ho = reinterpret_cast<const float4*>(hbn + s * 264 + p * 128 + s * 32);
#pragma unroll
                for (int i = 0; i < 8; ++i) {
                    float4 hv = ho[i];
                    ar = fmaf(WrO[i].x, hv.x, ar); ar = fmaf(WrO[i].y, hv.y, ar);
                    ar = fmaf(WrO[i].z, hv.z, ar); ar = fmaf(WrO[i].w, hv.w, ar);
                    az = fmaf(WzO[i].x, hv.x, az); az = fmaf(WzO[i].y, hv.y, az);
                    az = fmaf(WzO[i].z, hv.z, az); az = fmaf(WzO[i].w, hv.w, az);
                    an = fmaf(WnO[i].x, hv.x, an); an = fmaf(WnO[i].y, hv.y, an);
                    an = fmaf(WnO[i].z, hv.z, an); an = fmaf(WnO[i].w, hv.w, an);
                }
            }
            // complete partner-h poll; install into hbn; recompute partner's
            // pd-half locally, bit-exactly replicating the partner's tree:
            // xor1/2/4/8 butterfly within each 16-lane group == partner pdw[w_q]
            if (tid < 128) {
                const int qc = q * 128 + tid;
                const unsigned long long* slp = XHb + sl * 256 + qc;
                while ((unsigned int)(pk0 >> 32) < tag)
                    pk0 = __hip_atomic_load(slp, __ATOMIC_RELAXED, __HIP_MEMORY_SCOPE_AGENT);
                float v = __uint_as_float((unsigned int)pk0);
                hbn[qc] = v; hbn[264 + qc] = v; hbn[528 + qc] = v; hbn[792 + qc] = v;
                float pq = v * lwq;
                pq += __shfl_xor(pq, 1); pq += __shfl_xor(pq, 2);
                pq += __shfl_xor(pq, 4); pq += __shfl_xor(pq, 8);
                if ((lane & 15) == 0) qpd[tid >> 4] = pq;
            }
            bar_lds();  // B2 (LDS only): partner half of hbn + qpd in place

            // partner's ownpd, recomputed with the partner's exact tree order
            float pdq = ((qpd[0] + qpd[1]) + (qpd[2] + qpd[3]))
                      + ((qpd[4] + qpd[5]) + (qpd[6] + qpd[7]));

            // partner-half partial of A(t+1)
            {
                const float4* hq = reinterpret_cast<const float4*>(hbn + s * 264 + q * 128 + s * 32);
#pragma unroll
                for (int i = 0; i < 8; ++i) {
                    float4 hv = hq[i];
                    ar = fmaf(WrP[i].x, hv.x, ar); ar = fmaf(WrP[i].y, hv.y, ar);
                    ar = fmaf(WrP[i].z, hv.z, ar); ar = fmaf(WrP[i].w, hv.w, ar);
                    az = fmaf(WzP[i].x, hv.x, az); az = fmaf(WzP[i].y, hv.y, az);
                    az = fmaf(WzP[i].z, hv.z, az); az = fmaf(WzP[i].w, hv.w, az);
                    an = fmaf(WnP[i].x, hv.x, an); an = fmaf(WnP[i].y, hv.y, an);
                    an = fmaf(WnP[i].z, hv.z, an); an = fmaf(WnP[i].w, hv.w, an);
                }
            }
            ar += __shfl_xor(ar, 16); ar += __shfl_xor(ar, 32);
            az += __shfl_xor(az, 16); az += __shfl_xor(az, 32);
            an += __shfl_xor(an, 16); an += __shfl_xor(an, 32);
            sAr = ar; sAz = az; sAn = an;

            float dns = sigm_((ownpd + pdq) + lbv);  // commutative -> bit-identical in both WGs
            u = dns * bu; d = dns;
            skip = (u < 0.5f);
            ns++; hp ^= 1;
            gir = pr; giz = pz; gin = pn;
        }
    }
}

// ---------------------------------------------------------------------------
extern "C" void kernel_launch(void* const* d_in, const int* in_sizes, int n_in,
                              void* d_out, int out_size, void* d_ws, size_t ws_size,
                              hipStream_t stream)
{
    const float* x   = (const float*)d_in[0];  // (384,48,256)
    const float* hid = (const float*)d_in[1];  // (2,1,256)
    const float* wih = (const float*)d_in[2];  // (2,768,256)
    const float* whh = (const float*)d_in[3];  // (2,768,256)
    const float* bih = (const float*)d_in[4];  // (2,768)
    const float* bhh = (const float*)d_in[5];  // (2,768)
    const float* lw  = (const float*)d_in[6];  // (2,1,256)
    const float* lb  = (const float*)d_in[7];  // (2,1)
    float* out = (float*)d_out;

    float* ws = (float*)d_ws;
    float* GI = ws;                             // 18432*768 f32
    float* Y0 = GI + (size_t)18432 * 768;       // 18432*256 f32
    unsigned long long* XH0 = (unsigned long long*)(Y0 + (size_t)18432 * 256);
    unsigned long long* XH1 = XH0 + 48 * 512;   // 48 x [2][256] u64 per layer

    float* OUTy = out;                          // (384,48,256)
    float* HS   = out + (size_t)18432 * 256;    // (2,48,256)
    float* TU   = HS + 2 * 48 * 256;            // (48, 768)

    // tags must start at 0 (< first wanted tag 1) regardless of workspace poison
    hipMemsetAsync(XH0, 0, (size_t)(2 * 48 * 512) * sizeof(unsigned long long), stream);

    dim3 ggrid(12, 144), gblk(256);
    gemm_nt<<<ggrid, gblk, 0, stream>>>(x, wih, bih, GI);
    rec_layer<<<96, 512, 0, stream>>>(GI, Y0, whh, bhh, lw, lb, hid, XH0, HS, TU);
    gemm_nt<<<ggrid, gblk, 0, stream>>>(Y0, wih + 196608, bih + 768, GI);
    rec_layer<<<96, 512, 0, stream>>>(GI, OUTy, whh + 196608, bhh + 768, lw + 256, lb + 1,
                                      hid + 256, XH1, HS + 12288, TU + 384);
}

// Round 8
// 2469.141 us; speedup vs baseline: 4.5826x; 1.1266x over previous
//
#include <hip/hip_runtime.h>
#include <stdint.h>

// SkipGRU: T=384, B=48, C=H=256, L=2.
// GEMM(gi = x@W_ih^T + b_ih) -> pairwise-WG recurrence -> GEMM -> recurrence.
//
// Recurrence: 2 WGs per batch element. Register-file capacity is the hard
// constraint: W_hh = 768 KB > per-CU RF 512 KB; each WG holds half in
// registers (48 float4/lane @ 512 threads = 192 regs; cap 256 at 2 waves/EU).
// r4 (J=2 interleave) exceeded the cap -> scratch spill -> 6x regression.
//
// Sync lessons (r5, r6 both regressed): __syncthreads' vmcnt(0) drain is
// LOAD-BEARING for the exchange -- it forces the XH publish out to the
// coherence point and delays both WGs symmetrically, so the post-B1 poll's
// first check usually succeeds with ZERO retries. LDS-only barriers made the
// consumer arrive before the producer's store landed; each retry (newest VMEM
// op) then forced vmcnt(0) over the in-flight GI HBM loads. Keep __syncthreads.
//
// r8 = r7 with TWIN 48->32 (static LDS 82.3 KB -> 57.7 KB; r7's container
// died before pytest -- 82 KB static LDS per WG is the plausible launch-fail
// suspect under a 64 KB per-WG runtime cap; window size is not load-bearing
// for the theory). GI WINDOW STAGING IN LDS: r3's residual is B2's drain
// waiting ~500cy on mid-step GI HBM loads (GI streams 54 MB; FETCH_SIZE shows
// LLC doesn't retain it). With __syncthreads at both barriers, no placement of
// a ~900cy HBM load inside a ~1200cy two-barrier step avoids a drain stall.
// Fix: stage 32 steps of this WG's gi slice (32 x 384 f32 = 48 KB) once per
// window with coalesced float4 loads, read gi from LDS in the hot loop.
// Barrier drains then wait only on store acks (~200cy); retry vmcnt(0)s find
// nothing in flight; r3's poll dynamics preserved exactly.
//
// Exchange protocol (r2, verified): (tag<<32)|float_bits, tag = ns+1, slots
// double-buffered by parity; dns = sigm(pd_p+pd_q+lb) commutative -> bit-
// identical skip trajectories -> lockstep, no deadlock; overwrite-before-
// consume impossible (publish of k+2 requires consuming k+1, which required
// the partner consuming k).

#define T_STEPS 384
#define BATCH   48
#define HID     256
#define TWIN    32      // GI window (T_STEPS % TWIN == 0); 32*384 f32 = 48 KB

__device__ __forceinline__ float sigm_(float x) { return 1.f / (1.f + __expf(-x)); }
__device__ __forceinline__ float tanh_(float x) {
    float ax = fabsf(x);
    float e  = __expf(-2.f * ax);
    float r  = (1.f - e) / (1.f + e);
    return copysignf(r, x);
}

// ---------------------------------------------------------------------------
// GEMM: O[m][n] = sum_k X[m][k] * W[n][k] + B[n];  M=18432, N=768, K=256.
// grid (12, 144), block 256. Tile 128(M) x 64(N), K-chunks of 32 staged in LDS.
// (unchanged; not the current bottleneck)
// ---------------------------------------------------------------------------
__global__ __launch_bounds__(256, 2) void gemm_nt(const float* __restrict__ X,
                                                  const float* __restrict__ W,
                                                  const float* __restrict__ B,
                                                  float* __restrict__ O)
{
    __shared__ float As[32 * 140];
    __shared__ float Bs[32 * 68];

    const int tid = threadIdx.x;
    const int tx  = tid & 15;
    const int ty  = tid >> 4;
    const int n0  = blockIdx.x * 64;
    const int m0  = blockIdx.y * 128;

    float acc[8][4];
#pragma unroll
    for (int i = 0; i < 8; ++i)
#pragma unroll
        for (int j = 0; j < 4; ++j) acc[i][j] = 0.f;

    const float4 bias4 = *reinterpret_cast<const float4*>(B + n0 + tx * 4);

    for (int kc = 0; kc < 8; ++kc) {
        const int k0 = kc * 32;
        float4 a[4], bb[2];
#pragma unroll
        for (int j = 0; j < 4; ++j) {
            int f = tid + 256 * j, r = f >> 3, cq = f & 7;
            a[j] = *reinterpret_cast<const float4*>(X + (size_t)(m0 + r) * 256 + k0 + cq * 4);
        }
#pragma unroll
        for (int j = 0; j < 2; ++j) {
            int f = tid + 256 * j, r = f >> 3, cq = f & 7;
            bb[j] = *reinterpret_cast<const float4*>(W + (size_t)(n0 + r) * 256 + k0 + cq * 4);
        }
        __syncthreads();
#pragma unroll
        for (int j = 0; j < 4; ++j) {
            int f = tid + 256 * j, r = f >> 3, cq = f & 7;
            As[(cq * 4 + 0) * 140 + r] = a[j].x;
            As[(cq * 4 + 1) * 140 + r] = a[j].y;
            As[(cq * 4 + 2) * 140 + r] = a[j].z;
            As[(cq * 4 + 3) * 140 + r] = a[j].w;
        }
#pragma unroll
        for (int j = 0; j < 2; ++j) {
            int f = tid + 256 * j, r = f >> 3, cq = f & 7;
            Bs[(cq * 4 + 0) * 68 + r] = bb[j].x;
            Bs[(cq * 4 + 1) * 68 + r] = bb[j].y;
            Bs[(cq * 4 + 2) * 68 + r] = bb[j].z;
            Bs[(cq * 4 + 3) * 68 + r] = bb[j].w;
        }
        __syncthreads();
#pragma unroll 8
        for (int kk = 0; kk < 32; ++kk) {
            float4 av0 = *reinterpret_cast<const float4*>(As + kk * 140 + ty * 8);
            float4 av1 = *reinterpret_cast<const float4*>(As + kk * 140 + ty * 8 + 4);
            float4 bv  = *reinterpret_cast<const float4*>(Bs + kk * 68 + tx * 4);
            float am[8] = {av0.x, av0.y, av0.z, av0.w, av1.x, av1.y, av1.z, av1.w};
            float bn[4] = {bv.x, bv.y, bv.z, bv.w};
#pragma unroll
            for (int i = 0; i < 8; ++i)
#pragma unroll
                for (int j = 0; j < 4; ++j) acc[i][j] = fmaf(am[i], bn[j], acc[i][j]);
        }
    }
#pragma unroll
    for (int i = 0; i < 8; ++i) {
        int row = m0 + ty * 8 + i;
        float4 o;
        o.x = acc[i][0] + bias4.x;
        o.y = acc[i][1] + bias4.y;
        o.z = acc[i][2] + bias4.z;
        o.w = acc[i][3] + bias4.w;
        *reinterpret_cast<float4*>(O + (size_t)row * 768 + n0 + tx * 4) = o;
    }
}

// ---------------------------------------------------------------------------
// Recurrence. grid = 96 (p = blk/48, b = blk%48), block 512.
// WG p owns h-columns [p*128, p*128+128) and W_hh rows {c, 256+c, 512+c}.
// Wave w (0..7), g = lane&15 -> column c = p*128 + w*16 + g.
// Sub s = lane>>4: own k-slice [p*128+s*32,+32), partner [q*128+s*32,+32).
// hbuf: double-buffered (parity hp) x 4 shifted copies (stride 264) ->
// conflict-free broadcast b128 reads.
// ldsgi: TWIN steps x [3 gates x 128 cols] of this (b, half) gi slice.
// ---------------------------------------------------------------------------
__global__ __launch_bounds__(512, 2) void rec_layer(
    const float* __restrict__ GI, float* __restrict__ Yout,
    const float* __restrict__ whh, const float* __restrict__ bhh,
    const float* __restrict__ lwl, const float* __restrict__ lbl,
    const float* __restrict__ hid,
    unsigned long long* XH, unsigned long long* PD,
    float* __restrict__ hsout, float* __restrict__ tuout)
{
    __shared__ float4 ldsgi4[TWIN * 96];        // 32 x 384 floats = 48 KB
    __shared__ __align__(16) float hbuf[2112];  // 2 parities x (4 copies x 264)
    __shared__ float pdw[2][8];
    const float* ldsgi = reinterpret_cast<const float*>(ldsgi4);

    const int tid  = threadIdx.x;
    const int lane = tid & 63;
    const int w    = tid >> 6;
    const int g    = lane & 15;
    const int s    = lane >> 4;
    const int b    = blockIdx.x % 48;
    const int p    = blockIdx.x / 48;   // pair (i, i+48): same XCD under %8 round-robin
    const int q    = 1 - p;
    const int c    = p * 128 + w * 16 + g;
    const int cb   = w * 16 + g;        // column within own half

    // W_hh fragments (own-k and partner-k sub-slices); 48 float4/lane
    float4 WrO[8], WzO[8], WnO[8], WrP[8], WzP[8], WnP[8];
    {
        const size_t rR = (size_t)c * 256;
        const size_t rZ = (size_t)(256 + c) * 256;
        const size_t rN = (size_t)(512 + c) * 256;
        const int ko = p * 128 + s * 32;
        const int kq = q * 128 + s * 32;
        const float4* a  = reinterpret_cast<const float4*>(whh + rR + ko);
        const float4* bv = reinterpret_cast<const float4*>(whh + rZ + ko);
        const float4* cv = reinterpret_cast<const float4*>(whh + rN + ko);
        const float4* d4 = reinterpret_cast<const float4*>(whh + rR + kq);
        const float4* e4 = reinterpret_cast<const float4*>(whh + rZ + kq);
        const float4* f4 = reinterpret_cast<const float4*>(whh + rN + kq);
#pragma unroll
        for (int i = 0; i < 8; ++i) {
            WrO[i] = a[i];  WzO[i] = bv[i]; WnO[i] = cv[i];
            WrP[i] = d4[i]; WzP[i] = e4[i]; WnP[i] = f4[i];
        }
    }

    const float bhr = bhh[c], bhz = bhh[256 + c], bhn = bhh[512 + c];
    const float lwc = lwl[c];
    const float lbv = lbl[0];

    if (tid < 256) {
        float v = hid[tid];
        hbuf[tid] = v; hbuf[264 + tid] = v; hbuf[528 + tid] = v; hbuf[792 + tid] = v;
    }
    // initial GI window [0, TWIN): 3072 float4 loads, coalesced 512B runs
    {
        const float4* __restrict__ gsrc = reinterpret_cast<const float4*>(GI);
        for (int f = tid; f < TWIN * 96; f += 512) {
            int tt2  = f / 96;
            int r96  = f - tt2 * 96;
            int gate = r96 >> 5;
            int c4   = r96 & 31;
            size_t g4 = (((size_t)tt2 * 48 + b) * 768 + gate * 256 + p * 128) >> 2;
            ldsgi4[f] = gsrc[g4 + c4];
        }
    }
    __syncthreads();

    // prologue: stashed A(0) = W_hh . h(0)
    float sAr, sAz, sAn;
    {
        float ar = 0.f, az = 0.f, an = 0.f;
        const float4* ho = reinterpret_cast<const float4*>(hbuf + s * 264 + p * 128 + s * 32);
        const float4* hq = reinterpret_cast<const float4*>(hbuf + s * 264 + q * 128 + s * 32);
#pragma unroll
        for (int i = 0; i < 8; ++i) {
            float4 hv = ho[i];
            ar = fmaf(WrO[i].x, hv.x, ar); ar = fmaf(WrO[i].y, hv.y, ar);
            ar = fmaf(WrO[i].z, hv.z, ar); ar = fmaf(WrO[i].w, hv.w, ar);
            az = fmaf(WzO[i].x, hv.x, az); az = fmaf(WzO[i].y, hv.y, az);
            az = fmaf(WzO[i].z, hv.z, az); az = fmaf(WzO[i].w, hv.w, az);
            an = fmaf(WnO[i].x, hv.x, an); an = fmaf(WnO[i].y, hv.y, an);
            an = fmaf(WnO[i].z, hv.z, an); an = fmaf(WnO[i].w, hv.w, an);
        }
#pragma unroll
        for (int i = 0; i < 8; ++i) {
            float4 hv = hq[i];
            ar = fmaf(WrP[i].x, hv.x, ar); ar = fmaf(WrP[i].y, hv.y, ar);
            ar = fmaf(WrP[i].z, hv.z, ar); ar = fmaf(WrP[i].w, hv.w, ar);
            az = fmaf(WzP[i].x, hv.x, az); az = fmaf(WzP[i].y, hv.y, az);
            az = fmaf(WzP[i].z, hv.z, az); az = fmaf(WzP[i].w, hv.w, az);
            an = fmaf(WnP[i].x, hv.x, an); an = fmaf(WnP[i].y, hv.y, an);
            an = fmaf(WnP[i].z, hv.z, an); an = fmaf(WnP[i].w, hv.w, an);
        }
        ar += __shfl_xor(ar, 16); ar += __shfl_xor(ar, 32);
        az += __shfl_xor(az, 16); az += __shfl_xor(az, 32);
        an += __shfl_xor(an, 16); an += __shfl_xor(an, 32);
        sAr = ar; sAz = az; sAn = an;
    }

    float u = 1.f, d = 0.f;
    bool  skip = false;
    int   ns = 0;       // non-skip step counter; tag = ns+1, slot = ns&1
    int   hp = 0;       // hbuf parity
    int   tbase = 0;    // window base

    unsigned long long* XHb = XH + b * 512;
    unsigned long long* PDb = PD + b * 4;

    for (int t = 0; t < T_STEPS; ++t) {
        // window refill (once per TWIN steps; uniform condition; amortized)
        if (t - tbase == TWIN) {
            tbase = t;
            const float4* __restrict__ gsrc = reinterpret_cast<const float4*>(GI);
            for (int f = tid; f < TWIN * 96; f += 512) {
                int tt2  = f / 96;
                int r96  = f - tt2 * 96;
                int gate = r96 >> 5;
                int c4   = r96 & 31;
                size_t g4 = (((size_t)(t + tt2) * 48 + b) * 768 + gate * 256 + p * 128) >> 2;
                ldsgi4[f] = gsrc[g4 + c4];
            }
            __syncthreads();
        }
        const int tt = t - tbase;

        const float bu  = rintf(u);        // jnp.round == RNE
        const float obu = 1.f - bu;
        const size_t yrow = ((size_t)t * 48 + b) * 256;

        if (skip) {
            // new_h = h*(1-bu); new_u = clip(u+d,0,1)*(1-bu); d unchanged; no comm.
            float* hb = hbuf + hp * 1056;
            if (s == 0) {
                float hcv = hb[c];
                float nh  = hcv * obu;
                if (bu != 0.f) { hb[c] = nh; hb[264 + c] = nh; hb[528 + c] = nh; hb[792 + c] = nh; }
                Yout[yrow + c] = nh;
                if (t == T_STEPS - 1) hsout[b * 256 + c] = nh;
            }
            if (bu != 0.f) { sAr = 0.f; sAz = 0.f; sAn = 0.f; }  // h zeroed -> A zeroed
            if (p == 0 && tid == 0) tuout[b * 768 + t] = bu;
            u    = fminf(fmaxf(u + d, 0.f), 1.f) * obu;
            skip = (u < 0.5f);
            __syncthreads();
        } else {
            const int sl = ns & 1;
            const unsigned int tag = (unsigned int)ns + 1u;

            // gi(t) from LDS window (broadcast reads, conflict-free)
            const float gir = ldsgi[tt * 384 + cb];
            const float giz = ldsgi[tt * 384 + 128 + cb];
            const float gin = ldsgi[tt * 384 + 256 + cb];

            // gates from stashed A(t) + staged gi(t)
            float hcv = hbuf[hp * 1056 + s * 264 + c];  // old h[c]
            float rr  = sigm_(gir + sAr + bhr);
            float zz  = sigm_(giz + sAz + bhz);
            float tn  = tanh_(gin + rr * (sAn + bhn));
            float nh  = ((1.f - zz) * tn + zz * hcv) * bu;  // h_ns == new_h (not skipping)
            float pdv = nh * lwc;

            float* hbn = hbuf + (hp ^ 1) * 1056;   // next-parity buffer (no WAR hazard)
            if (s == 0) {
                unsigned long long pk = ((unsigned long long)tag << 32) |
                                        (unsigned long long)__float_as_uint(nh);
                __hip_atomic_store(XHb + sl * 256 + c, pk, __ATOMIC_RELAXED, __HIP_MEMORY_SCOPE_AGENT);
                hbn[c] = nh; hbn[264 + c] = nh; hbn[528 + c] = nh; hbn[792 + c] = nh;
                Yout[yrow + c] = nh;
                if (t == T_STEPS - 1) hsout[b * 256 + c] = nh;
            }
            // exact wave butterfly: 4 identical copies per column -> 4*S, *0.25 exact
            pdv += __shfl_xor(pdv, 1);  pdv += __shfl_xor(pdv, 2);  pdv += __shfl_xor(pdv, 4);
            pdv += __shfl_xor(pdv, 8);  pdv += __shfl_xor(pdv, 16); pdv += __shfl_xor(pdv, 32);
            pdv *= 0.25f;
            if (lane == 0) pdw[sl][w] = pdv;
            if (p == 0 && tid == 0) tuout[b * 768 + t] = bu;
            __syncthreads();  // B1: drain (stores only now) + own-half hbn + pdw visible

            float ownpd = ((pdw[sl][0] + pdw[sl][1]) + (pdw[sl][2] + pdw[sl][3]))
                        + ((pdw[sl][4] + pdw[sl][5]) + (pdw[sl][6] + pdw[sl][7]));
            if (tid == 0) {
                unsigned long long pk = ((unsigned long long)tag << 32) |
                                        (unsigned long long)__float_as_uint(ownpd);
                __hip_atomic_store(PDb + sl * 2 + p, pk, __ATOMIC_RELAXED, __HIP_MEMORY_SCOPE_AGENT);
            }
            // partner-h poll issue: flight hides under the own-half matvec
            unsigned long long pk0 = 0;
            if (tid < 128)
                pk0 = __hip_atomic_load(XHb + sl * 256 + q * 128 + tid, __ATOMIC_RELAXED, __HIP_MEMORY_SCOPE_AGENT);

            // own-half partial of A(t+1) (speculative; exact under skip rules)
            float ar = 0.f, az = 0.f, an = 0.f;
            {
                const float4* ho = reinterpret_cast<const float4*>(hbn + s * 264 + p * 128 + s * 32);
#pragma unroll
                for (int i = 0; i < 8; ++i) {
                    float4 hv = ho[i];
                    ar = fmaf(WrO[i].x, hv.x, ar); ar = fmaf(WrO[i].y, hv.y, ar);
                    ar = fmaf(WrO[i].z, hv.z, ar); ar = fmaf(WrO[i].w, hv.w, ar);
                    az = fmaf(WzO[i].x, hv.x, az); az = fmaf(WzO[i].y, hv.y, az);
                    az = fmaf(WzO[i].z, hv.z, az); az = fmaf(WzO[i].w, hv.w, az);
                    an = fmaf(WnO[i].x, hv.x, an); an = fmaf(WnO[i].y, hv.y, an);
                    an = fmaf(WnO[i].z, hv.z, an); an = fmaf(WnO[i].w, hv.w, an);
                }
            }
            // complete partner-h poll; nothing else in flight -> retries cost
            // only the poll load itself
            if (tid < 128) {
                const int qc = q * 128 + tid;
                const unsigned long long* slp = XHb + sl * 256 + qc;
                while ((unsigned int)(pk0 >> 32) < tag)
                    pk0 = __hip_atomic_load(slp, __ATOMIC_RELAXED, __HIP_MEMORY_SCOPE_AGENT);
                float v = __uint_as_float((unsigned int)pk0);
                hbn[qc] = v; hbn[264 + qc] = v; hbn[528 + qc] = v; hbn[792 + qc] = v;
            }
            __syncthreads();  // B2: partner half of hbn in place

            unsigned long long pkq = __hip_atomic_load(PDb + sl * 2 + q, __ATOMIC_RELAXED, __HIP_MEMORY_SCOPE_AGENT);

            // partner-half partial of A(t+1)
            {
                const float4* hq = reinterpret_cast<const float4*>(hbn + s * 264 + q * 128 + s * 32);
#pragma unroll
                for (int i = 0; i < 8; ++i) {
                    float4 hv = hq[i];
                    ar = fmaf(WrP[i].x, hv.x, ar); ar = fmaf(WrP[i].y, hv.y, ar);
                    ar = fmaf(WrP[i].z, hv.z, ar); ar = fmaf(WrP[i].w, hv.w, ar);
                    az = fmaf(WzP[i].x, hv.x, az); az = fmaf(WzP[i].y, hv.y, az);
                    az = fmaf(WzP[i].z, hv.z, az); az = fmaf(WzP[i].w, hv.w, az);
                    an = fmaf(WnP[i].x, hv.x, an); an = fmaf(WnP[i].y, hv.y, an);
                    an = fmaf(WnP[i].z, hv.z, an); an = fmaf(WnP[i].w, hv.w, an);
                }
            }
            ar += __shfl_xor(ar, 16); ar += __shfl_xor(ar, 32);
            az += __shfl_xor(az, 16); az += __shfl_xor(az, 32);
            an += __shfl_xor(an, 16); an += __shfl_xor(an, 32);
            sAr = ar; sAz = az; sAn = an;

            while ((unsigned int)(pkq >> 32) < tag)
                pkq = __hip_atomic_load(PDb + sl * 2 + q, __ATOMIC_RELAXED, __HIP_MEMORY_SCOPE_AGENT);
            const float pdq = __uint_as_float((unsigned int)pkq);

            float dns = sigm_((ownpd + pdq) + lbv);  // commutative -> bit-identical in both WGs
            u = dns * bu; d = dns;
            skip = (u < 0.5f);
            ns++; hp ^= 1;
        }
    }
}

// ---------------------------------------------------------------------------
extern "C" void kernel_launch(void* const* d_in, const int* in_sizes, int n_in,
                              void* d_out, int out_size, void* d_ws, size_t ws_size,
                              hipStream_t stream)
{
    const float* x   = (const float*)d_in[0];  // (384,48,256)
    const float* hid = (const float*)d_in[1];  // (2,1,256)
    const float* wih = (const float*)d_in[2];  // (2,768,256)
    const float* whh = (const float*)d_in[3];  // (2,768,256)
    const float* bih = (const float*)d_in[4];  // (2,768)
    const float* bhh = (const float*)d_in[5];  // (2,768)
    const float* lw  = (const float*)d_in[6];  // (2,1,256)
    const float* lb  = (const float*)d_in[7];  // (2,1)
    float* out = (float*)d_out;

    float* ws = (float*)d_ws;
    float* GI = ws;                             // 18432*768 f32
    float* Y0 = GI + (size_t)18432 * 768;       // 18432*256 f32
    unsigned long long* XH0 = (unsigned long long*)(Y0 + (size_t)18432 * 256);
    unsigned long long* XH1 = XH0 + 48 * 512;   // 48 x [2][256] u64 per layer
    unsigned long long* PD0 = XH1 + 48 * 512;   // 48 x [2][2] u64 per layer
    unsigned long long* PD1 = PD0 + 192;

    float* OUTy = out;                          // (384,48,256)
    float* HS   = out + (size_t)18432 * 256;    // (2,48,256)
    float* TU   = HS + 2 * 48 * 256;            // (48, 768)

    // tags must start at 0 (< first wanted tag 1) regardless of workspace poison
    hipMemsetAsync(XH0, 0, (size_t)(48 * 512 * 2 + 48 * 4 * 2) * sizeof(unsigned long long), stream);

    dim3 ggrid(12, 144), gblk(256);
    gemm_nt<<<ggrid, gblk, 0, stream>>>(x, wih, bih, GI);
    rec_layer<<<96, 512, 0, stream>>>(GI, Y0, whh, bhh, lw, lb, hid, XH0, PD0, HS, TU);
    gemm_nt<<<ggrid, gblk, 0, stream>>>(Y0, wih + 196608, bih + 768, GI);
    rec_layer<<<96, 512, 0, stream>>>(GI, OUTy, whh + 196608, bhh + 768, lw + 256, lb + 1,
                                      hid + 256, XH1, PD1, HS + 12288, TU + 384);
}

// Round 9
// 2064.247 us; speedup vs baseline: 5.4814x; 1.1961x over previous
//
#include <hip/hip_runtime.h>
#include <stdint.h>

// SkipGRU: T=384, B=48, C=H=256, L=2.
// GEMM(gi = x@W_ih^T + b_ih) -> pairwise-WG recurrence -> GEMM -> recurrence.
//
// Recurrence: 2 WGs per batch element (register-file capacity: W_hh = 768 KB >
// per-CU RF 512 KB; each WG holds half in registers, 48 float4/lane @ 512 thr).
// Exchange: self-synchronizing tagged u64 words ((tag<<32)|float_bits, poll
// until tag >= want), relaxed agent scope, slots double-buffered by parity.
//
// HARD-WON TIMING LESSONS (r4-r8, all regressed):
//  - r4: J=2 batch interleave -> VGPR cap (256/lane at 2 blocks/CU) exceeded,
//    W spilled to scratch, 6x slower. No extra per-step register state.
//  - r5: inline-asm sc0 poll carried s_waitcnt vmcnt(0) -> drained the GI
//    prefetch every retry. Polls must be compiler-tracked loads.
//  - r6: LDS-only barriers -> consumer checked the poll before the partner's
//    publish was visible -> retry storms (each retry ~LLC RT). __syncthreads'
//    vmcnt(0) drain + symmetric delay is LOAD-BEARING for poll timing.
//  - r8: GI staged in LDS (no VMEM in hot loop) -> ALSO a retry storm: r3's
//    mid-phase-2 GI HBM loads are accidental PACING -- the scheduler parks the
//    wave ~900cy before the poll check, by which time the publish is visible.
//    KEEP the GI loads exactly where r3 had them.
//
// r9 = r3 skeleton EXACTLY (928 us/layer, best verified) + wave-load-balance:
// after the shfl_xor folds all 4 s-subgroups hold IDENTICAL nh, so:
//  (1) each s-group writes its own hbuf copy (1 LDS store/lane, was 4 stores
//      on the s==0 group while 6 waves idled at the barrier);
//  (2) Yout/hsout stores move to the s==1 group (off the XH-publishing group);
//  (3) ALL 512 lanes poll the partner word for their column (4-way redundant,
//      same 8 cache lines) and each installs its own copy (was: 2 waves poll,
//      serial 4-store install). Distributed LDS writes are 2-way bank-aliased
//      (free). Poll-check timing relative to publish is UNCHANGED.

#define T_STEPS 384
#define BATCH   48
#define HID     256

__device__ __forceinline__ float sigm_(float x) { return 1.f / (1.f + __expf(-x)); }
__device__ __forceinline__ float tanh_(float x) {
    float ax = fabsf(x);
    float e  = __expf(-2.f * ax);
    float r  = (1.f - e) / (1.f + e);
    return copysignf(r, x);
}

// ---------------------------------------------------------------------------
// GEMM: O[m][n] = sum_k X[m][k] * W[n][k] + B[n];  M=18432, N=768, K=256.
// grid (12, 144), block 256. Tile 128(M) x 64(N), K-chunks of 32 staged in LDS.
// (unchanged; ~90 us each, not the current bottleneck)
// ---------------------------------------------------------------------------
__global__ __launch_bounds__(256, 2) void gemm_nt(const float* __restrict__ X,
                                                  const float* __restrict__ W,
                                                  const float* __restrict__ B,
                                                  float* __restrict__ O)
{
    __shared__ float As[32 * 140];
    __shared__ float Bs[32 * 68];

    const int tid = threadIdx.x;
    const int tx  = tid & 15;
    const int ty  = tid >> 4;
    const int n0  = blockIdx.x * 64;
    const int m0  = blockIdx.y * 128;

    float acc[8][4];
#pragma unroll
    for (int i = 0; i < 8; ++i)
#pragma unroll
        for (int j = 0; j < 4; ++j) acc[i][j] = 0.f;

    const float4 bias4 = *reinterpret_cast<const float4*>(B + n0 + tx * 4);

    for (int kc = 0; kc < 8; ++kc) {
        const int k0 = kc * 32;
        float4 a[4], bb[2];
#pragma unroll
        for (int j = 0; j < 4; ++j) {
            int f = tid + 256 * j, r = f >> 3, cq = f & 7;
            a[j] = *reinterpret_cast<const float4*>(X + (size_t)(m0 + r) * 256 + k0 + cq * 4);
        }
#pragma unroll
        for (int j = 0; j < 2; ++j) {
            int f = tid + 256 * j, r = f >> 3, cq = f & 7;
            bb[j] = *reinterpret_cast<const float4*>(W + (size_t)(n0 + r) * 256 + k0 + cq * 4);
        }
        __syncthreads();
#pragma unroll
        for (int j = 0; j < 4; ++j) {
            int f = tid + 256 * j, r = f >> 3, cq = f & 7;
            As[(cq * 4 + 0) * 140 + r] = a[j].x;
            As[(cq * 4 + 1) * 140 + r] = a[j].y;
            As[(cq * 4 + 2) * 140 + r] = a[j].z;
            As[(cq * 4 + 3) * 140 + r] = a[j].w;
        }
#pragma unroll
        for (int j = 0; j < 2; ++j) {
            int f = tid + 256 * j, r = f >> 3, cq = f & 7;
            Bs[(cq * 4 + 0) * 68 + r] = bb[j].x;
            Bs[(cq * 4 + 1) * 68 + r] = bb[j].y;
            Bs[(cq * 4 + 2) * 68 + r] = bb[j].z;
            Bs[(cq * 4 + 3) * 68 + r] = bb[j].w;
        }
        __syncthreads();
#pragma unroll 8
        for (int kk = 0; kk < 32; ++kk) {
            float4 av0 = *reinterpret_cast<const float4*>(As + kk * 140 + ty * 8);
            float4 av1 = *reinterpret_cast<const float4*>(As + kk * 140 + ty * 8 + 4);
            float4 bv  = *reinterpret_cast<const float4*>(Bs + kk * 68 + tx * 4);
            float am[8] = {av0.x, av0.y, av0.z, av0.w, av1.x, av1.y, av1.z, av1.w};
            float bn[4] = {bv.x, bv.y, bv.z, bv.w};
#pragma unroll
            for (int i = 0; i < 8; ++i)
#pragma unroll
                for (int j = 0; j < 4; ++j) acc[i][j] = fmaf(am[i], bn[j], acc[i][j]);
        }
    }
#pragma unroll
    for (int i = 0; i < 8; ++i) {
        int row = m0 + ty * 8 + i;
        float4 o;
        o.x = acc[i][0] + bias4.x;
        o.y = acc[i][1] + bias4.y;
        o.z = acc[i][2] + bias4.z;
        o.w = acc[i][3] + bias4.w;
        *reinterpret_cast<float4*>(O + (size_t)row * 768 + n0 + tx * 4) = o;
    }
}

// ---------------------------------------------------------------------------
// Recurrence. grid = 96 (p = blk/48, b = blk%48), block 512.
// WG p owns h-columns [p*128, p*128+128) and W_hh rows {c, 256+c, 512+c}.
// Wave w (0..7), g = lane&15 -> cb = w*16+g in [0,128), c = p*128 + cb.
// Sub s = lane>>4: own k-slice [p*128+s*32,+32), partner [q*128+s*32,+32).
// hbuf: double-buffered (parity hp) x 4 shifted copies (stride 264) ->
// conflict-free broadcast b128 reads; copy i is maintained by s-group i.
// ---------------------------------------------------------------------------
__global__ __launch_bounds__(512, 2) void rec_layer(
    const float* __restrict__ GI, float* __restrict__ Yout,
    const float* __restrict__ whh, const float* __restrict__ bhh,
    const float* __restrict__ lwl, const float* __restrict__ lbl,
    const float* __restrict__ hid,
    unsigned long long* XH, unsigned long long* PD,
    float* __restrict__ hsout, float* __restrict__ tuout)
{
    __shared__ float hbuf[2112];   // 2 parities x (4 copies x 264)
    __shared__ float pdw[2][8];    // double-buffered wave partials

    const int tid  = threadIdx.x;
    const int lane = tid & 63;
    const int w    = tid >> 6;
    const int g    = lane & 15;
    const int s    = lane >> 4;
    const int b    = blockIdx.x % 48;
    const int p    = blockIdx.x / 48;   // pair (i, i+48): same XCD under %8 round-robin
    const int q    = 1 - p;
    const int cb   = w * 16 + g;        // column within half, [0,128)
    const int c    = p * 128 + cb;

    // W_hh fragments (own-k and partner-k sub-slices); 48 float4/lane
    float4 WrO[8], WzO[8], WnO[8], WrP[8], WzP[8], WnP[8];
    {
        const size_t rR = (size_t)c * 256;
        const size_t rZ = (size_t)(256 + c) * 256;
        const size_t rN = (size_t)(512 + c) * 256;
        const int ko = p * 128 + s * 32;
        const int kq = q * 128 + s * 32;
        const float4* a  = reinterpret_cast<const float4*>(whh + rR + ko);
        const float4* bv = reinterpret_cast<const float4*>(whh + rZ + ko);
        const float4* cv = reinterpret_cast<const float4*>(whh + rN + ko);
        const float4* d4 = reinterpret_cast<const float4*>(whh + rR + kq);
        const float4* e4 = reinterpret_cast<const float4*>(whh + rZ + kq);
        const float4* f4 = reinterpret_cast<const float4*>(whh + rN + kq);
#pragma unroll
        for (int i = 0; i < 8; ++i) {
            WrO[i] = a[i];  WzO[i] = bv[i]; WnO[i] = cv[i];
            WrP[i] = d4[i]; WzP[i] = e4[i]; WnP[i] = f4[i];
        }
    }

    const float bhr = bhh[c], bhz = bhh[256 + c], bhn = bhh[512 + c];
    const float lwc = lwl[c];
    const float lbv = lbl[0];

    if (tid < 256) {
        float v = hid[tid];
        hbuf[tid] = v; hbuf[264 + tid] = v; hbuf[528 + tid] = v; hbuf[792 + tid] = v;
    }
    __syncthreads();

    // prologue: gi(0) + stashed A(0) = W_hh . h(0)
    float gir, giz, gin;
    {
        const size_t g0 = (size_t)b * 768 + c;
        gir = GI[g0]; giz = GI[g0 + 256]; gin = GI[g0 + 512];
    }
    float sAr, sAz, sAn;
    {
        float ar = 0.f, az = 0.f, an = 0.f;
        const float4* ho = reinterpret_cast<const float4*>(hbuf + s * 264 + p * 128 + s * 32);
        const float4* hq = reinterpret_cast<const float4*>(hbuf + s * 264 + q * 128 + s * 32);
#pragma unroll
        for (int i = 0; i < 8; ++i) {
            float4 hv = ho[i];
            ar = fmaf(WrO[i].x, hv.x, ar); ar = fmaf(WrO[i].y, hv.y, ar);
            ar = fmaf(WrO[i].z, hv.z, ar); ar = fmaf(WrO[i].w, hv.w, ar);
            az = fmaf(WzO[i].x, hv.x, az); az = fmaf(WzO[i].y, hv.y, az);
            az = fmaf(WzO[i].z, hv.z, az); az = fmaf(WzO[i].w, hv.w, az);
            an = fmaf(WnO[i].x, hv.x, an); an = fmaf(WnO[i].y, hv.y, an);
            an = fmaf(WnO[i].z, hv.z, an); an = fmaf(WnO[i].w, hv.w, an);
        }
#pragma unroll
        for (int i = 0; i < 8; ++i) {
            float4 hv = hq[i];
            ar = fmaf(WrP[i].x, hv.x, ar); ar = fmaf(WrP[i].y, hv.y, ar);
            ar = fmaf(WrP[i].z, hv.z, ar); ar = fmaf(WrP[i].w, hv.w, ar);
            az = fmaf(WzP[i].x, hv.x, az); az = fmaf(WzP[i].y, hv.y, az);
            az = fmaf(WzP[i].z, hv.z, az); az = fmaf(WzP[i].w, hv.w, az);
            an = fmaf(WnP[i].x, hv.x, an); an = fmaf(WnP[i].y, hv.y, an);
            an = fmaf(WnP[i].z, hv.z, an); an = fmaf(WnP[i].w, hv.w, an);
        }
        ar += __shfl_xor(ar, 16); ar += __shfl_xor(ar, 32);
        az += __shfl_xor(az, 16); az += __shfl_xor(az, 32);
        an += __shfl_xor(an, 16); an += __shfl_xor(an, 32);
        sAr = ar; sAz = az; sAn = an;
    }

    float u = 1.f, d = 0.f;
    bool  skip = false;
    int   ns = 0;   // non-skip step counter; tag = ns+1, slot = ns&1
    int   hp = 0;   // hbuf parity

    unsigned long long* XHb = XH + b * 512;
    unsigned long long* PDb = PD + b * 4;

    for (int t = 0; t < T_STEPS; ++t) {
        const float bu  = rintf(u);        // jnp.round == RNE
        const float obu = 1.f - bu;
        const size_t yrow = ((size_t)t * 48 + b) * 256;
        const int tp = (t < T_STEPS - 1) ? t + 1 : t;
        const size_t gpb = ((size_t)tp * 48 + b) * 768 + c;

        if (skip) {
            // new_h = h*(1-bu); new_u = clip(u+d,0,1)*(1-bu); d unchanged; no comm.
            float* hb = hbuf + hp * 1056;
            float hcv = hb[s * 264 + c];             // own copy (identical across s)
            float nh  = hcv * obu;
            if (bu != 0.f) hb[s * 264 + c] = nh;     // distributed in-place update
            if (s == 1) {
                Yout[yrow + c] = nh;
                if (t == T_STEPS - 1) hsout[b * 256 + c] = nh;
            }
            if (bu != 0.f) { sAr = 0.f; sAz = 0.f; sAn = 0.f; }  // h zeroed -> A zeroed
            if (p == 0 && tid == 0) tuout[b * 768 + t] = bu;
            float pr = GI[gpb], pz = GI[gpb + 256], pn = GI[gpb + 512];  // gi(t+1) prefetch
            u    = fminf(fmaxf(u + d, 0.f), 1.f) * obu;
            skip = (u < 0.5f);
            __syncthreads();
            gir = pr; giz = pz; gin = pn;
        } else {
            const int sl = ns & 1;
            const unsigned int tag = (unsigned int)ns + 1u;

            // gates from stashed A(t) + prefetched gi(t)
            float hcv = hbuf[hp * 1056 + s * 264 + c];  // old h[c]
            float rr  = sigm_(gir + sAr + bhr);
            float zz  = sigm_(giz + sAz + bhz);
            float tn  = tanh_(gin + rr * (sAn + bhn));
            float nh  = ((1.f - zz) * tn + zz * hcv) * bu;  // h_ns == new_h (not skipping)
            float pdv = nh * lwc;

            float* hbn = hbuf + (hp ^ 1) * 1056;   // next-parity buffer (no WAR hazard)
            hbn[s * 264 + c] = nh;                 // distributed copy write (was 4x on s==0)
            if (s == 0) {
                unsigned long long pk0p = ((unsigned long long)tag << 32) |
                                          (unsigned long long)__float_as_uint(nh);
                __hip_atomic_store(XHb + sl * 256 + c, pk0p, __ATOMIC_RELAXED, __HIP_MEMORY_SCOPE_AGENT);
            } else if (s == 1) {
                Yout[yrow + c] = nh;
                if (t == T_STEPS - 1) hsout[b * 256 + c] = nh;
            }
            // exact wave butterfly: 4 identical copies per column -> 4*S, *0.25 exact
            pdv += __shfl_xor(pdv, 1);  pdv += __shfl_xor(pdv, 2);  pdv += __shfl_xor(pdv, 4);
            pdv += __shfl_xor(pdv, 8);  pdv += __shfl_xor(pdv, 16); pdv += __shfl_xor(pdv, 32);
            pdv *= 0.25f;
            if (lane == 0) pdw[sl][w] = pdv;
            if (p == 0 && tid == 0) tuout[b * 768 + t] = bu;
            __syncthreads();  // B1: publish drained (vmcnt), own-half copies + pdw visible

            float ownpd = ((pdw[sl][0] + pdw[sl][1]) + (pdw[sl][2] + pdw[sl][3]))
                        + ((pdw[sl][4] + pdw[sl][5]) + (pdw[sl][6] + pdw[sl][7]));
            if (tid == 0) {
                unsigned long long pkp = ((unsigned long long)tag << 32) |
                                         (unsigned long long)__float_as_uint(ownpd);
                __hip_atomic_store(PDb + sl * 2 + p, pkp, __ATOMIC_RELAXED, __HIP_MEMORY_SCOPE_AGENT);
            }
            // partner poll issue by ALL lanes (each lane owns partner col cb,
            // 4-way s-redundant); flight hides under GI prefetch + matvec
            unsigned long long pk0 =
                __hip_atomic_load(XHb + sl * 256 + q * 128 + cb, __ATOMIC_RELAXED, __HIP_MEMORY_SCOPE_AGENT);
            // gi(t+1) prefetch: ALSO the accidental pacing that lets the
            // publish become visible before the poll check (r8 lesson)
            float pr = GI[gpb], pz = GI[gpb + 256], pn = GI[gpb + 512];

            // own-half partial of A(t+1) (speculative; exact under skip rules)
            float ar = 0.f, az = 0.f, an = 0.f;
            {
                const float4* ho = reinterpret_cast<const float4*>(hbn + s * 264 + p * 128 + s * 32);
#pragma unroll
                for (int i = 0; i < 8; ++i) {
                    float4 hv = ho[i];
                    ar = fmaf(WrO[i].x, hv.x, ar); ar = fmaf(WrO[i].y, hv.y, ar);
                    ar = fmaf(WrO[i].z, hv.z, ar); ar = fmaf(WrO[i].w, hv.w, ar);
                    az = fmaf(WzO[i].x, hv.x, az); az = fmaf(WzO[i].y, hv.y, az);
                    az = fmaf(WzO[i].z, hv.z, az); az = fmaf(WzO[i].w, hv.w, az);
                    an = fmaf(WnO[i].x, hv.x, an); an = fmaf(WnO[i].y, hv.y, an);
                    an = fmaf(WnO[i].z, hv.z, an); an = fmaf(WnO[i].w, hv.w, an);
                }
            }
            // complete partner poll; each lane installs its OWN copy (1 store)
            {
                const int qc = q * 128 + cb;
                const unsigned long long* slp = XHb + sl * 256 + qc;
                while ((unsigned int)(pk0 >> 32) < tag)
                    pk0 = __hip_atomic_load(slp, __ATOMIC_RELAXED, __HIP_MEMORY_SCOPE_AGENT);
                hbn[s * 264 + qc] = __uint_as_float((unsigned int)pk0);
            }
            __syncthreads();  // B2: partner half of all copies in place

            unsigned long long pkq = __hip_atomic_load(PDb + sl * 2 + q, __ATOMIC_RELAXED, __HIP_MEMORY_SCOPE_AGENT);

            // partner-half partial of A(t+1)
            {
                const float4* hq = reinterpret_cast<const float4*>(hbn + s * 264 + q * 128 + s * 32);
#pragma unroll
                for (int i = 0; i < 8; ++i) {
                    float4 hv = hq[i];
                    ar = fmaf(WrP[i].x, hv.x, ar); ar = fmaf(WrP[i].y, hv.y, ar);
                    ar = fmaf(WrP[i].z, hv.z, ar); ar = fmaf(WrP[i].w, hv.w, ar);
                    az = fmaf(WzP[i].x, hv.x, az); az = fmaf(WzP[i].y, hv.y, az);
                    az = fmaf(WzP[i].z, hv.z, az); az = fmaf(WzP[i].w, hv.w, az);
                    an = fmaf(WnP[i].x, hv.x, an); an = fmaf(WnP[i].y, hv.y, an);
                    an = fmaf(WnP[i].z, hv.z, an); an = fmaf(WnP[i].w, hv.w, an);
                }
            }
            ar += __shfl_xor(ar, 16); ar += __shfl_xor(ar, 32);
            az += __shfl_xor(az, 16); az += __shfl_xor(az, 32);
            an += __shfl_xor(an, 16); an += __shfl_xor(an, 32);
            sAr = ar; sAz = az; sAn = an;

            while ((unsigned int)(pkq >> 32) < tag)
                pkq = __hip_atomic_load(PDb + sl * 2 + q, __ATOMIC_RELAXED, __HIP_MEMORY_SCOPE_AGENT);
            const float pdq = __uint_as_float((unsigned int)pkq);

            float dns = sigm_((ownpd + pdq) + lbv);  // commutative -> bit-identical in both WGs
            u = dns * bu; d = dns;
            skip = (u < 0.5f);
            ns++; hp ^= 1;
            gir = pr; giz = pz; gin = pn;
        }
    }
}

// ---------------------------------------------------------------------------
extern "C" void kernel_launch(void* const* d_in, const int* in_sizes, int n_in,
                              void* d_out, int out_size, void* d_ws, size_t ws_size,
                              hipStream_t stream)
{
    const float* x   = (const float*)d_in[0];  // (384,48,256)
    const float* hid = (const float*)d_in[1];  // (2,1,256)
    const float* wih = (const float*)d_in[2];  // (2,768,256)
    const float* whh = (const float*)d_in[3];  // (2,768,256)
    const float* bih = (const float*)d_in[4];  // (2,768)
    const float* bhh = (const float*)d_in[5];  // (2,768)
    const float* lw  = (const float*)d_in[6];  // (2,1,256)
    const float* lb  = (const float*)d_in[7];  // (2,1)
    float* out = (float*)d_out;

    float* ws = (float*)d_ws;
    float* GI = ws;                             // 18432*768 f32
    float* Y0 = GI + (size_t)18432 * 768;       // 18432*256 f32
    unsigned long long* XH0 = (unsigned long long*)(Y0 + (size_t)18432 * 256);
    unsigned long long* XH1 = XH0 + 48 * 512;   // 48 x [2][256] u64 per layer
    unsigned long long* PD0 = XH1 + 48 * 512;   // 48 x [2][2] u64 per layer
    unsigned long long* PD1 = PD0 + 192;

    float* OUTy = out;                          // (384,48,256)
    float* HS   = out + (size_t)18432 * 256;    // (2,48,256)
    float* TU   = HS + 2 * 48 * 256;            // (48, 768)

    // tags must start at 0 (< first wanted tag 1) regardless of workspace poison
    hipMemsetAsync(XH0, 0, (size_t)(48 * 512 * 2 + 48 * 4 * 2) * sizeof(unsigned long long), stream);

    dim3 ggrid(12, 144), gblk(256);
    gemm_nt<<<ggrid, gblk, 0, stream>>>(x, wih, bih, GI);
    rec_layer<<<96, 512, 0, stream>>>(GI, Y0, whh, bhh, lw, lb, hid, XH0, PD0, HS, TU);
    gemm_nt<<<ggrid, gblk, 0, stream>>>(Y0, wih + 196608, bih + 768, GI);
    rec_layer<<<96, 512, 0, stream>>>(GI, OUTy, whh + 196608, bhh + 768, lw + 256, lb + 1,
                                      hid + 256, XH1, PD1, HS + 12288, TU + 384);
}

// Round 10
// 1985.837 us; speedup vs baseline: 5.6978x; 1.0395x over previous
//
#include <hip/hip_runtime.h>
#include <stdint.h>

// SkipGRU: T=384, B=48, C=H=256, L=2.
// r10: FUSED CROSS-LAYER PIPELINE. r9's falsifier fired (load-balance delta
// ~0): the per-step floor is the exchange RT + pacing chain, immovable within
// a "pair marches one step at a time" structure. The remaining 2x lever is
// that the two 925us rec layers ran SERIALLY (same-stream kernels) although
// layer-2 step t depends only on layer-1 step t. This kernel runs
// GEMM1 -> one mega-kernel with 208 co-resident WGs:
//   A (96) : layer-1 rec pair (r9 verbatim: GI1 HBM prefetch pacing kept),
//            minus Y0 store (was only GEMM2 input), plus y1(t) publish into a
//            16-deep tagged ring Y1X every step (tag t+1).
//   B (16) : gi2 producers. Each holds half of W_ih2 in regs (192 regs, same
//            matvec structure), serves 6 batches: poll y1(t), compute
//            gi2(t) = W_ih2.y1(t)+b_ih2, publish to tagged ring GI2X.
//   C (96) : layer-2 rec pair (r9 verbatim), GI-prefetch slot replaced by
//            GI2X tagged polls at the SAME phase position; writes OUTy/HS/TU.
// Deadlock-freedom: 208 blocks <= 256 CUs (1 WG/CU) -> all resident at
// launch. Mutual waits only within pairs (r2-verified protocol). A->B->C
// deps forward-only on persistent tagged slots; ring reuse guarded by
// progress counters (D=16), each wait released by a consumer whose inputs
// are already published (acyclic). Tags/progress zeroed per launch.
// Timing lessons kept: A's mid-phase-2 GI1 HBM loads (pacing, r8), plain
// __syncthreads (r6), compiler-tracked polls (r5), no extra register state
// beyond +-8 regs (r4: cap is 256/lane).

#define T_STEPS 384
typedef unsigned long long u64t;

__device__ __forceinline__ float sigm_(float x) { return 1.f / (1.f + __expf(-x)); }
__device__ __forceinline__ float tanh_(float x) {
    float ax = fabsf(x);
    float e  = __expf(-2.f * ax);
    float r  = (1.f - e) / (1.f + e);
    return copysignf(r, x);
}

// ---------------------------------------------------------------------------
// GEMM1: O[m][n] = sum_k X[m][k]*W[n][k] + B[n]; M=18432, N=768, K=256.
// (unchanged)
// ---------------------------------------------------------------------------
__global__ __launch_bounds__(256, 2) void gemm_nt(const float* __restrict__ X,
                                                  const float* __restrict__ W,
                                                  const float* __restrict__ B,
                                                  float* __restrict__ O)
{
    __shared__ float As[32 * 140];
    __shared__ float Bs[32 * 68];

    const int tid = threadIdx.x;
    const int tx  = tid & 15;
    const int ty  = tid >> 4;
    const int n0  = blockIdx.x * 64;
    const int m0  = blockIdx.y * 128;

    float acc[8][4];
#pragma unroll
    for (int i = 0; i < 8; ++i)
#pragma unroll
        for (int j = 0; j < 4; ++j) acc[i][j] = 0.f;

    const float4 bias4 = *reinterpret_cast<const float4*>(B + n0 + tx * 4);

    for (int kc = 0; kc < 8; ++kc) {
        const int k0 = kc * 32;
        float4 a[4], bb[2];
#pragma unroll
        for (int j = 0; j < 4; ++j) {
            int f = tid + 256 * j, r = f >> 3, cq = f & 7;
            a[j] = *reinterpret_cast<const float4*>(X + (size_t)(m0 + r) * 256 + k0 + cq * 4);
        }
#pragma unroll
        for (int j = 0; j < 2; ++j) {
            int f = tid + 256 * j, r = f >> 3, cq = f & 7;
            bb[j] = *reinterpret_cast<const float4*>(W + (size_t)(n0 + r) * 256 + k0 + cq * 4);
        }
        __syncthreads();
#pragma unroll
        for (int j = 0; j < 4; ++j) {
            int f = tid + 256 * j, r = f >> 3, cq = f & 7;
            As[(cq * 4 + 0) * 140 + r] = a[j].x;
            As[(cq * 4 + 1) * 140 + r] = a[j].y;
            As[(cq * 4 + 2) * 140 + r] = a[j].z;
            As[(cq * 4 + 3) * 140 + r] = a[j].w;
        }
#pragma unroll
        for (int j = 0; j < 2; ++j) {
            int f = tid + 256 * j, r = f >> 3, cq = f & 7;
            Bs[(cq * 4 + 0) * 68 + r] = bb[j].x;
            Bs[(cq * 4 + 1) * 68 + r] = bb[j].y;
            Bs[(cq * 4 + 2) * 68 + r] = bb[j].z;
            Bs[(cq * 4 + 3) * 68 + r] = bb[j].w;
        }
        __syncthreads();
#pragma unroll 8
        for (int kk = 0; kk < 32; ++kk) {
            float4 av0 = *reinterpret_cast<const float4*>(As + kk * 140 + ty * 8);
            float4 av1 = *reinterpret_cast<const float4*>(As + kk * 140 + ty * 8 + 4);
            float4 bv  = *reinterpret_cast<const float4*>(Bs + kk * 68 + tx * 4);
            float am[8] = {av0.x, av0.y, av0.z, av0.w, av1.x, av1.y, av1.z, av1.w};
            float bn[4] = {bv.x, bv.y, bv.z, bv.w};
#pragma unroll
            for (int i = 0; i < 8; ++i)
#pragma unroll
                for (int j = 0; j < 4; ++j) acc[i][j] = fmaf(am[i], bn[j], acc[i][j]);
        }
    }
#pragma unroll
    for (int i = 0; i < 8; ++i) {
        int row = m0 + ty * 8 + i;
        float4 o;
        o.x = acc[i][0] + bias4.x;
        o.y = acc[i][1] + bias4.y;
        o.z = acc[i][2] + bias4.z;
        o.w = acc[i][3] + bias4.w;
        *reinterpret_cast<float4*>(O + (size_t)row * 768 + n0 + tx * 4) = o;
    }
}

// ---------------------------------------------------------------------------
__global__ __launch_bounds__(512, 2) void fused_pipe(
    const float* __restrict__ GI1,
    const float* __restrict__ wih2, const float* __restrict__ bih2,
    const float* __restrict__ whh1, const float* __restrict__ bhh1,
    const float* __restrict__ whh2, const float* __restrict__ bhh2,
    const float* __restrict__ lw1, const float* __restrict__ lb1,
    const float* __restrict__ lw2, const float* __restrict__ lb2,
    const float* __restrict__ hid1, const float* __restrict__ hid2,
    u64t* XH1, u64t* PD1, u64t* XH2, u64t* PD2,
    u64t* Y1X, u64t* GI2X, unsigned int* BPROG, unsigned int* CPROG,
    float* __restrict__ OUTy, float* __restrict__ HS, float* __restrict__ TU)
{
    __shared__ float hbuf[2112];   // A/C: 2 parities x 4 copies x 264
    __shared__ float pdw[2][8];
    __shared__ float ybuf[6336];   // B: 6 batches x (4 copies x 264)

    const int tid  = threadIdx.x;
    const int lane = tid & 63;
    const int w    = tid >> 6;
    const int g    = lane & 15;
    const int s    = lane >> 4;
    const int blk  = blockIdx.x;

    if (blk < 192) {
        // ================= roles A (blk<96) and C (96..191): rec pair ======
        const bool isA = (blk < 96);
        const int rb   = isA ? blk : (blk - 96);
        const int b    = rb % 48;
        const int p    = rb / 48;
        const int q    = 1 - p;
        const int cb   = w * 16 + g;
        const int c    = p * 128 + cb;

        const float* whh = isA ? whh1 : whh2;
        const float* bhh = isA ? bhh1 : bhh2;
        const float* lwl = isA ? lw1 : lw2;
        const float* lbl = isA ? lb1 : lb2;
        const float* hid = isA ? hid1 : hid2;
        u64t* XHb = (isA ? XH1 : XH2) + b * 512;
        u64t* PDb = (isA ? PD1 : PD2) + b * 4;

        float4 WrO[8], WzO[8], WnO[8], WrP[8], WzP[8], WnP[8];
        {
            const size_t rR = (size_t)c * 256;
            const size_t rZ = (size_t)(256 + c) * 256;
            const size_t rN = (size_t)(512 + c) * 256;
            const int ko = p * 128 + s * 32;
            const int kq = q * 128 + s * 32;
            const float4* a  = reinterpret_cast<const float4*>(whh + rR + ko);
            const float4* bv = reinterpret_cast<const float4*>(whh + rZ + ko);
            const float4* cv = reinterpret_cast<const float4*>(whh + rN + ko);
            const float4* d4 = reinterpret_cast<const float4*>(whh + rR + kq);
            const float4* e4 = reinterpret_cast<const float4*>(whh + rZ + kq);
            const float4* f4 = reinterpret_cast<const float4*>(whh + rN + kq);
#pragma unroll
            for (int i = 0; i < 8; ++i) {
                WrO[i] = a[i];  WzO[i] = bv[i]; WnO[i] = cv[i];
                WrP[i] = d4[i]; WzP[i] = e4[i]; WnP[i] = f4[i];
            }
        }
        const float bhr = bhh[c], bhz = bhh[256 + c], bhn = bhh[512 + c];
        const float lwc = lwl[c];
        const float lbv = lbl[0];

        if (tid < 256) {
            float v = hid[tid];
            hbuf[tid] = v; hbuf[264 + tid] = v; hbuf[528 + tid] = v; hbuf[792 + tid] = v;
        }
        __syncthreads();

        // gi(0): A reads GEMM1 output; C issues ring polls (checked at t=0 top)
        float gir = 0.f, giz = 0.f, gin = 0.f;
        u64t pkr = 0, pkz = 0, pkn = 0;
        if (isA) {
            const size_t g0 = (size_t)b * 768 + c;
            gir = GI1[g0]; giz = GI1[g0 + 256]; gin = GI1[g0 + 512];
        } else {
            const u64t* g0 = GI2X + ((size_t)b * 16) * 768 + c;
            pkr = __hip_atomic_load(g0,       __ATOMIC_RELAXED, __HIP_MEMORY_SCOPE_AGENT);
            pkz = __hip_atomic_load(g0 + 256, __ATOMIC_RELAXED, __HIP_MEMORY_SCOPE_AGENT);
            pkn = __hip_atomic_load(g0 + 512, __ATOMIC_RELAXED, __HIP_MEMORY_SCOPE_AGENT);
        }

        float sAr, sAz, sAn;
        {
            float ar = 0.f, az = 0.f, an = 0.f;
            const float4* ho = reinterpret_cast<const float4*>(hbuf + s * 264 + p * 128 + s * 32);
            const float4* hq = reinterpret_cast<const float4*>(hbuf + s * 264 + q * 128 + s * 32);
#pragma unroll
            for (int i = 0; i < 8; ++i) {
                float4 hv = ho[i];
                ar = fmaf(WrO[i].x, hv.x, ar); ar = fmaf(WrO[i].y, hv.y, ar);
                ar = fmaf(WrO[i].z, hv.z, ar); ar = fmaf(WrO[i].w, hv.w, ar);
                az = fmaf(WzO[i].x, hv.x, az); az = fmaf(WzO[i].y, hv.y, az);
                az = fmaf(WzO[i].z, hv.z, az); az = fmaf(WzO[i].w, hv.w, az);
                an = fmaf(WnO[i].x, hv.x, an); an = fmaf(WnO[i].y, hv.y, an);
                an = fmaf(WnO[i].z, hv.z, an); an = fmaf(WnO[i].w, hv.w, an);
            }
#pragma unroll
            for (int i = 0; i < 8; ++i) {
                float4 hv = hq[i];
                ar = fmaf(WrP[i].x, hv.x, ar); ar = fmaf(WrP[i].y, hv.y, ar);
                ar = fmaf(WrP[i].z, hv.z, ar); ar = fmaf(WrP[i].w, hv.w, ar);
                az = fmaf(WzP[i].x, hv.x, az); az = fmaf(WzP[i].y, hv.y, az);
                az = fmaf(WzP[i].z, hv.z, az); az = fmaf(WzP[i].w, hv.w, az);
                an = fmaf(WnP[i].x, hv.x, an); an = fmaf(WnP[i].y, hv.y, an);
                an = fmaf(WnP[i].z, hv.z, an); an = fmaf(WnP[i].w, hv.w, an);
            }
            ar += __shfl_xor(ar, 16); ar += __shfl_xor(ar, 32);
            az += __shfl_xor(az, 16); az += __shfl_xor(az, 32);
            an += __shfl_xor(an, 16); an += __shfl_xor(an, 32);
            sAr = ar; sAz = az; sAn = an;
        }

        float* hsout = isA ? HS : (HS + 12288);
        float* tubase = TU + (isA ? 0 : 384);
        u64t*  Y1b = Y1X + (size_t)b * 16 * 256;

        float u = 1.f, d = 0.f;
        bool  skip = false;
        int   ns = 0, hp = 0, bcap = 16;

        for (int t = 0; t < T_STEPS; ++t) {
            const float bu  = rintf(u);        // jnp.round == RNE
            const float obu = 1.f - bu;
            const int tp = (t < T_STEPS - 1) ? t + 1 : t;
            const size_t gpb = ((size_t)tp * 48 + b) * 768 + c;   // A only
            const u64t* gnext = GI2X + ((size_t)b * 16 + (tp & 15)) * 768 + c; // C only
            const size_t yrow = ((size_t)t * 48 + b) * 256;

            // A: ring backpressure vs B (uniform; rare refresh)
            if (isA && t >= bcap) {
                unsigned int m;
                do {
                    unsigned int p0 = __hip_atomic_load(BPROG + b * 2,     __ATOMIC_RELAXED, __HIP_MEMORY_SCOPE_AGENT);
                    unsigned int p1 = __hip_atomic_load(BPROG + b * 2 + 1, __ATOMIC_RELAXED, __HIP_MEMORY_SCOPE_AGENT);
                    m = p0 < p1 ? p0 : p1;
                } while ((int)m < t - 15);
                bcap = (int)m + 16;
            }
            u64t* yslot = Y1b + (size_t)(t & 15) * 256;

            if (skip) {
                float* hb = hbuf + hp * 1056;
                float hcv = hb[s * 264 + c];
                float nh  = hcv * obu;
                if (bu != 0.f) hb[s * 264 + c] = nh;
                if (s == 0) {
                    if (isA) {
                        u64t pk = ((u64t)(unsigned)(t + 1) << 32) | (u64t)__float_as_uint(nh);
                        __hip_atomic_store(yslot + c, pk, __ATOMIC_RELAXED, __HIP_MEMORY_SCOPE_AGENT);
                    }
                } else if (s == 1) {
                    if (!isA) OUTy[yrow + c] = nh;
                    if (t == T_STEPS - 1) hsout[b * 256 + c] = nh;
                }
                if (bu != 0.f) { sAr = 0.f; sAz = 0.f; sAn = 0.f; }
                if (p == 0 && tid == 0) tubase[b * 768 + t] = bu;
                if (!isA && tid == 0)
                    __hip_atomic_store(CPROG + b * 2 + p, (unsigned)(t + 1), __ATOMIC_RELAXED, __HIP_MEMORY_SCOPE_AGENT);
                float pr = 0.f, pz = 0.f, pn = 0.f;
                if (isA) { pr = GI1[gpb]; pz = GI1[gpb + 256]; pn = GI1[gpb + 512]; }
                else {
                    pkr = __hip_atomic_load(gnext,       __ATOMIC_RELAXED, __HIP_MEMORY_SCOPE_AGENT);
                    pkz = __hip_atomic_load(gnext + 256, __ATOMIC_RELAXED, __HIP_MEMORY_SCOPE_AGENT);
                    pkn = __hip_atomic_load(gnext + 512, __ATOMIC_RELAXED, __HIP_MEMORY_SCOPE_AGENT);
                }
                u    = fminf(fmaxf(u + d, 0.f), 1.f) * obu;
                skip = (u < 0.5f);
                __syncthreads();
                if (isA) { gir = pr; giz = pz; gin = pn; }
            } else {
                const int sl = ns & 1;
                const unsigned int tag = (unsigned)ns + 1u;

                if (!isA) {
                    // complete gi2(t) polls (usually 0 retries: B leads C)
                    const u64t* gcur = GI2X + ((size_t)b * 16 + (t & 15)) * 768 + c;
                    const unsigned int wt = (unsigned)(t + 1);
                    while ((unsigned)(pkr >> 32) < wt)
                        pkr = __hip_atomic_load(gcur,       __ATOMIC_RELAXED, __HIP_MEMORY_SCOPE_AGENT);
                    while ((unsigned)(pkz >> 32) < wt)
                        pkz = __hip_atomic_load(gcur + 256, __ATOMIC_RELAXED, __HIP_MEMORY_SCOPE_AGENT);
                    while ((unsigned)(pkn >> 32) < wt)
                        pkn = __hip_atomic_load(gcur + 512, __ATOMIC_RELAXED, __HIP_MEMORY_SCOPE_AGENT);
                    gir = __uint_as_float((unsigned)pkr);
                    giz = __uint_as_float((unsigned)pkz);
                    gin = __uint_as_float((unsigned)pkn);
                }

                float hcv = hbuf[hp * 1056 + s * 264 + c];
                float rr  = sigm_(gir + sAr + bhr);
                float zz  = sigm_(giz + sAz + bhz);
                float tn  = tanh_(gin + rr * (sAn + bhn));
                float nh  = ((1.f - zz) * tn + zz * hcv) * bu;
                float pdv = nh * lwc;

                float* hbn = hbuf + (hp ^ 1) * 1056;
                hbn[s * 264 + c] = nh;
                if (s == 0) {
                    u64t pkx = ((u64t)tag << 32) | (u64t)__float_as_uint(nh);
                    __hip_atomic_store(XHb + sl * 256 + c, pkx, __ATOMIC_RELAXED, __HIP_MEMORY_SCOPE_AGENT);
                    if (isA) {
                        u64t pky = ((u64t)(unsigned)(t + 1) << 32) | (u64t)__float_as_uint(nh);
                        __hip_atomic_store(yslot + c, pky, __ATOMIC_RELAXED, __HIP_MEMORY_SCOPE_AGENT);
                    }
                } else if (s == 1) {
                    if (!isA) OUTy[yrow + c] = nh;
                    if (t == T_STEPS - 1) hsout[b * 256 + c] = nh;
                }
                pdv += __shfl_xor(pdv, 1);  pdv += __shfl_xor(pdv, 2);  pdv += __shfl_xor(pdv, 4);
                pdv += __shfl_xor(pdv, 8);  pdv += __shfl_xor(pdv, 16); pdv += __shfl_xor(pdv, 32);
                pdv *= 0.25f;
                if (lane == 0) pdw[sl][w] = pdv;
                if (p == 0 && tid == 0) tubase[b * 768 + t] = bu;
                if (!isA && tid == 0)
                    __hip_atomic_store(CPROG + b * 2 + p, (unsigned)(t + 1), __ATOMIC_RELAXED, __HIP_MEMORY_SCOPE_AGENT);
                __syncthreads();  // B1

                float ownpd = ((pdw[sl][0] + pdw[sl][1]) + (pdw[sl][2] + pdw[sl][3]))
                            + ((pdw[sl][4] + pdw[sl][5]) + (pdw[sl][6] + pdw[sl][7]));
                if (tid == 0) {
                    u64t pkp = ((u64t)tag << 32) | (u64t)__float_as_uint(ownpd);
                    __hip_atomic_store(PDb + sl * 2 + p, pkp, __ATOMIC_RELAXED, __HIP_MEMORY_SCOPE_AGENT);
                }
                u64t pk0 = __hip_atomic_load(XHb + sl * 256 + q * 128 + cb, __ATOMIC_RELAXED, __HIP_MEMORY_SCOPE_AGENT);
                // mid-phase-2 prefetch slot (pacing position, r8 lesson)
                float pr = 0.f, pz = 0.f, pn = 0.f;
                if (isA) { pr = GI1[gpb]; pz = GI1[gpb + 256]; pn = GI1[gpb + 512]; }
                else {
                    pkr = __hip_atomic_load(gnext,       __ATOMIC_RELAXED, __HIP_MEMORY_SCOPE_AGENT);
                    pkz = __hip_atomic_load(gnext + 256, __ATOMIC_RELAXED, __HIP_MEMORY_SCOPE_AGENT);
                    pkn = __hip_atomic_load(gnext + 512, __ATOMIC_RELAXED, __HIP_MEMORY_SCOPE_AGENT);
                }

                float ar = 0.f, az = 0.f, an = 0.f;
                {
                    const float4* ho = reinterpret_cast<const float4*>(hbn + s * 264 + p * 128 + s * 32);
#pragma unroll
                    for (int i = 0; i < 8; ++i) {
                        float4 hv = ho[i];
                        ar = fmaf(WrO[i].x, hv.x, ar); ar = fmaf(WrO[i].y, hv.y, ar);
                        ar = fmaf(WrO[i].z, hv.z, ar); ar = fmaf(WrO[i].w, hv.w, ar);
                        az = fmaf(WzO[i].x, hv.x, az); az = fmaf(WzO[i].y, hv.y, az);
                        az = fmaf(WzO[i].z, hv.z, az); az = fmaf(WzO[i].w, hv.w, az);
                        an = fmaf(WnO[i].x, hv.x, an); an = fmaf(WnO[i].y, hv.y, an);
                        an = fmaf(WnO[i].z, hv.z, an); an = fmaf(WnO[i].w, hv.w, an);
                    }
                }
                {
                    const int qc = q * 128 + cb;
                    const u64t* slp = XHb + sl * 256 + qc;
                    while ((unsigned)(pk0 >> 32) < tag)
                        pk0 = __hip_atomic_load(slp, __ATOMIC_RELAXED, __HIP_MEMORY_SCOPE_AGENT);
                    hbn[s * 264 + qc] = __uint_as_float((unsigned)pk0);
                }
                __syncthreads();  // B2

                u64t pkq = __hip_atomic_load(PDb + sl * 2 + q, __ATOMIC_RELAXED, __HIP_MEMORY_SCOPE_AGENT);
                {
                    const float4* hq = reinterpret_cast<const float4*>(hbn + s * 264 + q * 128 + s * 32);
#pragma unroll
                    for (int i = 0; i < 8; ++i) {
                        float4 hv = hq[i];
                        ar = fmaf(WrP[i].x, hv.x, ar); ar = fmaf(WrP[i].y, hv.y, ar);
                        ar = fmaf(WrP[i].z, hv.z, ar); ar = fmaf(WrP[i].w, hv.w, ar);
                        az = fmaf(WzP[i].x, hv.x, az); az = fmaf(WzP[i].y, hv.y, az);
                        az = fmaf(WzP[i].z, hv.z, az); az = fmaf(WzP[i].w, hv.w, az);
                        an = fmaf(WnP[i].x, hv.x, an); an = fmaf(WnP[i].y, hv.y, an);
                        an = fmaf(WnP[i].z, hv.z, an); an = fmaf(WnP[i].w, hv.w, an);
                    }
                }
                ar += __shfl_xor(ar, 16); ar += __shfl_xor(ar, 32);
                az += __shfl_xor(az, 16); az += __shfl_xor(az, 32);
                an += __shfl_xor(an, 16); an += __shfl_xor(an, 32);
                sAr = ar; sAz = az; sAn = an;

                while ((unsigned)(pkq >> 32) < tag)
                    pkq = __hip_atomic_load(PDb + sl * 2 + q, __ATOMIC_RELAXED, __HIP_MEMORY_SCOPE_AGENT);
                const float pdq = __uint_as_float((unsigned)pkq);

                float dns = sigm_((ownpd + pdq) + lbv);  // commutative -> lockstep
                u = dns * bu; d = dns;
                skip = (u < 0.5f);
                ns++; hp ^= 1;
                if (isA) { gir = pr; giz = pz; gin = pn; }
            }
        }
    } else {
        // ================= role B: gi2 producer ============================
        const int j   = blk - 192;       // 0..15
        const int hf  = j & 1;
        const int b0  = (j >> 1) * 6;    // 6 batches per WG
        const int cb2 = w * 16 + g;
        const int c2  = hf * 128 + cb2;

        float4 Wr[16], Wz[16], Wn[16];
        {
            const float4* r4 = reinterpret_cast<const float4*>(wih2 + (size_t)c2 * 256 + s * 64);
            const float4* z4 = reinterpret_cast<const float4*>(wih2 + (size_t)(256 + c2) * 256 + s * 64);
            const float4* n4 = reinterpret_cast<const float4*>(wih2 + (size_t)(512 + c2) * 256 + s * 64);
#pragma unroll
            for (int i = 0; i < 16; ++i) { Wr[i] = r4[i]; Wz[i] = z4[i]; Wn[i] = n4[i]; }
        }
        const float bR = bih2[c2], bZ = bih2[256 + c2], bN = bih2[512 + c2];

        int ccap[6];
#pragma unroll
        for (int i = 0; i < 6; ++i) ccap[i] = 16;

        const int i0 = tid, i1 = tid + 512, i2 = tid + 1024;
        const int bb0 = i0 >> 8, co0 = i0 & 255;
        const int bb1 = i1 >> 8, co1 = i1 & 255;
        const int bb2 = i2 >> 8, co2 = i2 & 255;

        for (int t = 0; t < T_STEPS; ++t) {
            const int slot = t & 15;
            const unsigned int wt = (unsigned)(t + 1);
            const u64t* a0 = Y1X + ((size_t)(b0 + bb0) * 16 + slot) * 256 + co0;
            const u64t* a1 = Y1X + ((size_t)(b0 + bb1) * 16 + slot) * 256 + co1;
            const u64t* a2 = Y1X + ((size_t)(b0 + bb2) * 16 + slot) * 256 + co2;
            u64t v0 = __hip_atomic_load(a0, __ATOMIC_RELAXED, __HIP_MEMORY_SCOPE_AGENT);
            u64t v1 = __hip_atomic_load(a1, __ATOMIC_RELAXED, __HIP_MEMORY_SCOPE_AGENT);
            u64t v2 = __hip_atomic_load(a2, __ATOMIC_RELAXED, __HIP_MEMORY_SCOPE_AGENT);
            while ((unsigned)(v0 >> 32) < wt) v0 = __hip_atomic_load(a0, __ATOMIC_RELAXED, __HIP_MEMORY_SCOPE_AGENT);
            while ((unsigned)(v1 >> 32) < wt) v1 = __hip_atomic_load(a1, __ATOMIC_RELAXED, __HIP_MEMORY_SCOPE_AGENT);
            while ((unsigned)(v2 >> 32) < wt) v2 = __hip_atomic_load(a2, __ATOMIC_RELAXED, __HIP_MEMORY_SCOPE_AGENT);
            {
                float v = __uint_as_float((unsigned)v0); float* yb = ybuf + bb0 * 1056;
                yb[co0] = v; yb[264 + co0] = v; yb[528 + co0] = v; yb[792 + co0] = v;
            }
            {
                float v = __uint_as_float((unsigned)v1); float* yb = ybuf + bb1 * 1056;
                yb[co1] = v; yb[264 + co1] = v; yb[528 + co1] = v; yb[792 + co1] = v;
            }
            {
                float v = __uint_as_float((unsigned)v2); float* yb = ybuf + bb2 * 1056;
                yb[co2] = v; yb[264 + co2] = v; yb[528 + co2] = v; yb[792 + co2] = v;
            }
            __syncthreads();
            if (tid < 6)
                __hip_atomic_store(BPROG + (b0 + tid) * 2 + hf, wt, __ATOMIC_RELAXED, __HIP_MEMORY_SCOPE_AGENT);
#pragma unroll
            for (int bb = 0; bb < 6; ++bb) {
                if (t >= ccap[bb]) {   // ring backpressure vs C (uniform, rare)
                    unsigned int m;
                    do {
                        m = __hip_atomic_load(CPROG + (b0 + bb) * 2 + hf, __ATOMIC_RELAXED, __HIP_MEMORY_SCOPE_AGENT);
                    } while ((int)m < t - 15);
                    ccap[bb] = (int)m + 16;
                }
                float ar = 0.f, az = 0.f, an = 0.f;
                const float4* yv = reinterpret_cast<const float4*>(ybuf + bb * 1056 + s * 328);
#pragma unroll
                for (int i = 0; i < 16; ++i) {
                    float4 hv = yv[i];
                    ar = fmaf(Wr[i].x, hv.x, ar); ar = fmaf(Wr[i].y, hv.y, ar);
                    ar = fmaf(Wr[i].z, hv.z, ar); ar = fmaf(Wr[i].w, hv.w, ar);
                    az = fmaf(Wz[i].x, hv.x, az); az = fmaf(Wz[i].y, hv.y, az);
                    az = fmaf(Wz[i].z, hv.z, az); az = fmaf(Wz[i].w, hv.w, az);
                    an = fmaf(Wn[i].x, hv.x, an); an = fmaf(Wn[i].y, hv.y, an);
                    an = fmaf(Wn[i].z, hv.z, an); an = fmaf(Wn[i].w, hv.w, an);
                }
                ar += __shfl_xor(ar, 16); ar += __shfl_xor(ar, 32);
                az += __shfl_xor(az, 16); az += __shfl_xor(az, 32);
                an += __shfl_xor(an, 16); an += __shfl_xor(an, 32);
                ar += bR; az += bZ; an += bN;
                if (s < 3) {
                    float v = (s == 0) ? ar : ((s == 1) ? az : an);
                    u64t pk = ((u64t)wt << 32) | (u64t)__float_as_uint(v);
                    __hip_atomic_store(GI2X + ((size_t)(b0 + bb) * 16 + slot) * 768 + s * 256 + c2,
                                       pk, __ATOMIC_RELAXED, __HIP_MEMORY_SCOPE_AGENT);
                }
            }
            __syncthreads();  // ybuf reuse guard
        }
    }
}

// ---------------------------------------------------------------------------
extern "C" void kernel_launch(void* const* d_in, const int* in_sizes, int n_in,
                              void* d_out, int out_size, void* d_ws, size_t ws_size,
                              hipStream_t stream)
{
    const float* x   = (const float*)d_in[0];  // (384,48,256)
    const float* hid = (const float*)d_in[1];  // (2,1,256)
    const float* wih = (const float*)d_in[2];  // (2,768,256)
    const float* whh = (const float*)d_in[3];  // (2,768,256)
    const float* bih = (const float*)d_in[4];  // (2,768)
    const float* bhh = (const float*)d_in[5];  // (2,768)
    const float* lw  = (const float*)d_in[6];  // (2,1,256)
    const float* lb  = (const float*)d_in[7];  // (2,1)
    float* out = (float*)d_out;

    float* ws = (float*)d_ws;
    float* GI = ws;                                   // 18432*768 f32
    u64t* XH1 = (u64t*)(GI + (size_t)18432 * 768);    // 48*512
    u64t* XH2 = XH1 + 24576;
    u64t* PD1 = XH2 + 24576;                          // 48*4
    u64t* PD2 = PD1 + 192;
    u64t* Y1X = PD2 + 192;                            // 48*16*256
    u64t* GI2X = Y1X + 196608;                        // 48*16*768
    unsigned int* BPROG = (unsigned int*)(GI2X + 589824);  // 48*2
    unsigned int* CPROG = BPROG + 96;                      // 48*2

    float* OUTy = out;                                // (384,48,256)
    float* HS   = out + (size_t)18432 * 256;          // (2,48,256)
    float* TU   = HS + 2 * 48 * 256;                  // (48, 768)

    // zero all tags/progress each launch (graph-replay safe):
    // (24576*2 + 192*2 + 196608 + 589824) u64 + 192 u32
    hipMemsetAsync(XH1, 0, (size_t)835968 * sizeof(u64t) + 768, stream);

    dim3 ggrid(12, 144), gblk(256);
    gemm_nt<<<ggrid, gblk, 0, stream>>>(x, wih, bih, GI);
    fused_pipe<<<208, 512, 0, stream>>>(GI,
        wih + 196608, bih + 768,
        whh, bhh, whh + 196608, bhh + 768,
        lw, lb, lw + 256, lb + 1,
        hid, hid + 256,
        XH1, PD1, XH2, PD2, Y1X, GI2X, BPROG, CPROG,
        OUTy, HS, TU);
}